// Round 3
// baseline (542.018 us; speedup 1.0000x reference)
//
#include <hip/hip_runtime.h>
#include <hip/hip_bf16.h>
#include <math.h>
#include <stdint.h>

#define EPS 1e-5f

typedef int v4i __attribute__((ext_vector_type(4)));

__device__ __forceinline__ void glds16(const void* g, void* l) {
  __builtin_amdgcn_global_load_lds(
      (const __attribute__((address_space(1))) void*)g,
      (__attribute__((address_space(3))) void*)l, 16, 0, 0);
}

__device__ __forceinline__ signed char q8(float f, float xs) {
  float r = rintf(f * xs);
  r = fminf(fmaxf(r, -128.f), 127.f);
  return (signed char)(int)r;
}

__device__ __forceinline__ float bf2f(unsigned short h) {
  return __builtin_bit_cast(float, (unsigned)h << 16);
}

// ---------------- merged weight abs-sum (3 tensors, 1 launch) ----------------
__global__ __launch_bounds__(256) void absum3_kernel(const float* __restrict__ Wg,
                                                     const float* __restrict__ W1,
                                                     const float* __restrict__ W2,
                                                     float* __restrict__ out) {
  int blk = blockIdx.x;
  const float* w; long n4; float* o; long lb; long nb;
  if (blk < 512)      { w = Wg; n4 = 3932160; o = &out[0]; lb = blk;       nb = 512; }
  else if (blk < 768) { w = W1; n4 = 1048576; o = &out[1]; lb = blk - 512; nb = 256; }
  else                { w = W2; n4 = 1048576; o = &out[2]; lb = blk - 768; nb = 256; }
  const float4* w4 = (const float4*)w;
  float s = 0.f;
  for (long i = lb * 256 + threadIdx.x; i < n4; i += nb * 256) {
    float4 v = w4[i];
    s += fabsf(v.x) + fabsf(v.y) + fabsf(v.z) + fabsf(v.w);
  }
  for (int off = 32; off; off >>= 1) s += __shfl_down(s, off);
  __shared__ float sb[4];
  int lane = threadIdx.x & 63, wid = threadIdx.x >> 6;
  if (lane == 0) sb[wid] = s;
  __syncthreads();
  if (threadIdx.x == 0) atomicAdd(o, sb[0] + sb[1] + sb[2] + sb[3]);
}

// ---------------- merged ternarize (3 tensors, 1 launch) ----------------
__global__ __launch_bounds__(256) void ternarize3_kernel(const float* __restrict__ Wg,
                                                         const float* __restrict__ W1,
                                                         const float* __restrict__ W2,
                                                         signed char* __restrict__ tg,
                                                         signed char* __restrict__ t1,
                                                         signed char* __restrict__ t2,
                                                         const float* __restrict__ sums) {
  int blk = blockIdx.x;
  const float* w; signed char* t; long n4; float ws; long lb; long nb;
  if (blk < 1024) {
    w = Wg; t = tg; n4 = 3932160; ws = sums[0] * (1.f / 15728640.f) + EPS; lb = blk; nb = 1024;
  } else if (blk < 1536) {
    w = W1; t = t1; n4 = 1048576; ws = sums[1] * (1.f / 4194304.f) + EPS; lb = blk - 1024; nb = 512;
  } else {
    w = W2; t = t2; n4 = 1048576; ws = sums[2] * (1.f / 4194304.f) + EPS; lb = blk - 1536; nb = 512;
  }
  const float4* w4 = (const float4*)w;
  char4* t4 = (char4*)t;
  for (long i = lb * 256 + threadIdx.x; i < n4; i += nb * 256) {
    float4 v = w4[i];
    char4 c;
    c.x = (signed char)(int)fminf(fmaxf(rintf(v.x / ws), -1.f), 1.f);
    c.y = (signed char)(int)fminf(fmaxf(rintf(v.y / ws), -1.f), 1.f);
    c.z = (signed char)(int)fminf(fmaxf(rintf(v.z / ws), -1.f), 1.f);
    c.w = (signed char)(int)fminf(fmaxf(rintf(v.w / ws), -1.f), 1.f);
    t4[i] = c;
  }
}

// ---------------- LN1: write xn fp32 + per-row absmax ----------------
__global__ __launch_bounds__(256) void ln_rowmax_kernel(const float* __restrict__ x,
                                                        const float* __restrict__ w,
                                                        const float* __restrict__ b,
                                                        float* __restrict__ xn,
                                                        float* __restrict__ rowmax) {
  int m = blockIdx.x;
  int tid = threadIdx.x, lane = tid & 63, wid = tid >> 6;
  __shared__ float sb[4];
  float4 v = ((const float4*)(x + (long)m * 1024))[tid];
  float s = v.x + v.y + v.z + v.w;
  for (int off = 32; off; off >>= 1) s += __shfl_down(s, off);
  if (lane == 0) sb[wid] = s;
  __syncthreads();
  float mean = (sb[0] + sb[1] + sb[2] + sb[3]) * (1.f / 1024.f);
  __syncthreads();
  float dx = v.x - mean, dy = v.y - mean, dz = v.z - mean, dw = v.w - mean;
  float ss = dx * dx + dy * dy + dz * dz + dw * dw;
  for (int off = 32; off; off >>= 1) ss += __shfl_down(ss, off);
  if (lane == 0) sb[wid] = ss;
  __syncthreads();
  float rstd = rsqrtf((sb[0] + sb[1] + sb[2] + sb[3]) * (1.f / 1024.f) + EPS);
  __syncthreads();
  float4 wv = ((const float4*)w)[tid];
  float4 bv = ((const float4*)b)[tid];
  float4 o;
  o.x = dx * rstd * wv.x + bv.x;
  o.y = dy * rstd * wv.y + bv.y;
  o.z = dz * rstd * wv.z + bv.z;
  o.w = dw * rstd * wv.w + bv.w;
  ((float4*)(xn + (long)m * 1024))[tid] = o;
  float mx = fmaxf(fmaxf(fabsf(o.x), fabsf(o.y)), fmaxf(fabsf(o.z), fabsf(o.w)));
  for (int off = 32; off; off >>= 1) mx = fmaxf(mx, __shfl_down(mx, off));
  if (lane == 0) sb[wid] = mx;
  __syncthreads();
  if (tid == 0) rowmax[m] = fmaxf(fmaxf(sb[0], sb[1]), fmaxf(sb[2], sb[3]));
}

// ---------------- quantA: per-dest-row combined scale + gather-quantize ----------------
__global__ __launch_bounds__(256) void quantA_kernel(const float* __restrict__ xn,
                                                     const int* __restrict__ is0,
                                                     const int* __restrict__ is1,
                                                     const int* __restrict__ iv,
                                                     const float* __restrict__ rowmax,
                                                     const float* __restrict__ sums,
                                                     signed char* __restrict__ Aq,
                                                     float* __restrict__ s1) {
  int m = blockIdx.x;
  int b = m >> 8, l = m & 255;
  const float* rm = rowmax + b * 256;
  int src[15];
  src[0] = l;
#pragma unroll
  for (int j = 0; j < 3; ++j) { src[1 + j] = is0[l * 3 + j]; src[4 + j] = is1[l * 3 + j]; }
#pragma unroll
  for (int j = 0; j < 8; ++j) src[7 + j] = iv[l * 8 + j];
  float c = EPS;
#pragma unroll
  for (int sl = 0; sl < 15; ++sl) c = fmaxf(c, rm[src[sl]]);
  float xs = 127.f / c;
  if (threadIdx.x == 0) s1[m] = (sums[0] * (1.f / 15728640.f) + EPS) * c * (1.f / 127.f);
#pragma unroll
  for (int sl = 0; sl < 15; ++sl) {
    float4 v = ((const float4*)(xn + ((long)(b << 8) + src[sl]) * 1024))[threadIdx.x];
    char4 cc;
    cc.x = q8(v.x, xs); cc.y = q8(v.y, xs); cc.z = q8(v.z, xs); cc.w = q8(v.w, xs);
    *(char4*)&Aq[(long)m * 15360 + sl * 1024 + threadIdx.x * 4] = cc;
  }
}

// ---------------- fused: xag = x + s1*(acc0+acc1); LN2; quantize to int8 ----------------
__global__ __launch_bounds__(256) void ln_quant_acc_kernel(const int* __restrict__ accA,
                                                           const int* accB,
                                                           const float* __restrict__ x,
                                                           const float* __restrict__ s1,
                                                           const float* __restrict__ w,
                                                           const float* __restrict__ bb,
                                                           float* xag,
                                                           signed char* __restrict__ q,
                                                           float* __restrict__ srow,
                                                           const float* __restrict__ sum_ptr,
                                                           float inv_n) {
  int m = blockIdx.x;
  int tid = threadIdx.x, lane = tid & 63, wid = tid >> 6;
  __shared__ float sb[4];
  float sm = s1[m];
  int4 a0 = ((const int4*)(accA + (long)m * 1024))[tid];
  int4 a1 = ((const int4*)(accB + (long)m * 1024))[tid];
  float4 xv = ((const float4*)(x + (long)m * 1024))[tid];
  float4 v;
  v.x = xv.x + sm * (float)(a0.x + a1.x);
  v.y = xv.y + sm * (float)(a0.y + a1.y);
  v.z = xv.z + sm * (float)(a0.z + a1.z);
  v.w = xv.w + sm * (float)(a0.w + a1.w);
  ((float4*)(xag + (long)m * 1024))[tid] = v;
  float s = v.x + v.y + v.z + v.w;
  for (int off = 32; off; off >>= 1) s += __shfl_down(s, off);
  if (lane == 0) sb[wid] = s;
  __syncthreads();
  float mean = (sb[0] + sb[1] + sb[2] + sb[3]) * (1.f / 1024.f);
  __syncthreads();
  float dx = v.x - mean, dy = v.y - mean, dz = v.z - mean, dw = v.w - mean;
  float ss = dx * dx + dy * dy + dz * dz + dw * dw;
  for (int off = 32; off; off >>= 1) ss += __shfl_down(ss, off);
  if (lane == 0) sb[wid] = ss;
  __syncthreads();
  float rstd = rsqrtf((sb[0] + sb[1] + sb[2] + sb[3]) * (1.f / 1024.f) + EPS);
  __syncthreads();
  float4 wv = ((const float4*)w)[tid];
  float4 bv = ((const float4*)bb)[tid];
  float nx = dx * rstd * wv.x + bv.x;
  float ny = dy * rstd * wv.y + bv.y;
  float nz = dz * rstd * wv.z + bv.z;
  float nw = dw * rstd * wv.w + bv.w;
  float mx = fmaxf(fmaxf(fabsf(nx), fabsf(ny)), fmaxf(fabsf(nz), fabsf(nw)));
  for (int off = 32; off; off >>= 1) mx = fmaxf(mx, __shfl_down(mx, off));
  if (lane == 0) sb[wid] = mx;
  __syncthreads();
  float rmax = fmaxf(fmaxf(fmaxf(sb[0], sb[1]), fmaxf(sb[2], sb[3])), EPS);
  float xs = 127.f / rmax;
  char4 c;
  c.x = q8(nx, xs); c.y = q8(ny, xs); c.z = q8(nz, xs); c.w = q8(nw, xs);
  *(char4*)&q[(long)m * 1024 + tid * 4] = c;
  if (tid == 0) srow[m] = (sum_ptr[0] * inv_n + EPS) * rmax * (1.f / 127.f);
}

// ---------------- row quantize [8192,4096] bf16 -> int8 ----------------
__global__ __launch_bounds__(256) void rowquant4k_kernel(const unsigned short* __restrict__ g,
                                                         signed char* __restrict__ q,
                                                         float* __restrict__ srow,
                                                         const float* __restrict__ sum_ptr,
                                                         float inv_n) {
  int m = blockIdx.x;
  int tid = threadIdx.x, lane = tid & 63, wid = tid >> 6;
  __shared__ float sb[4];
  const uint4* gr = (const uint4*)(g + (long)m * 4096);  // 16B = 8 bf16
  float f[16];
  float mx = 0.f;
#pragma unroll
  for (int i = 0; i < 2; ++i) {
    uint4 u = gr[tid + i * 256];
    unsigned uu[4] = {u.x, u.y, u.z, u.w};
#pragma unroll
    for (int j = 0; j < 4; ++j) {
      float lo = bf2f((unsigned short)(uu[j] & 0xFFFF));
      float hi = bf2f((unsigned short)(uu[j] >> 16));
      f[i * 8 + j * 2] = lo;
      f[i * 8 + j * 2 + 1] = hi;
      mx = fmaxf(mx, fmaxf(fabsf(lo), fabsf(hi)));
    }
  }
  for (int off = 32; off; off >>= 1) mx = fmaxf(mx, __shfl_down(mx, off));
  if (lane == 0) sb[wid] = mx;
  __syncthreads();
  float rmax = fmaxf(fmaxf(fmaxf(sb[0], sb[1]), fmaxf(sb[2], sb[3])), EPS);
  float xs = 127.f / rmax;
#pragma unroll
  for (int i = 0; i < 2; ++i) {
    char4 c0, c1;
    c0.x = q8(f[i * 8 + 0], xs); c0.y = q8(f[i * 8 + 1], xs);
    c0.z = q8(f[i * 8 + 2], xs); c0.w = q8(f[i * 8 + 3], xs);
    c1.x = q8(f[i * 8 + 4], xs); c1.y = q8(f[i * 8 + 5], xs);
    c1.z = q8(f[i * 8 + 6], xs); c1.w = q8(f[i * 8 + 7], xs);
    long base = (long)m * 4096 + (tid + i * 256) * 8;
    *(char4*)&q[base] = c0;
    *(char4*)&q[base + 4] = c1;
  }
  if (tid == 0) srow[m] = (sum_ptr[0] * inv_n + EPS) * rmax * (1.f / 127.f);
}

// ---------------- final residual: out = xag + s3*(acc0+acc1) ----------------
__global__ __launch_bounds__(256) void reduce3_kernel(const int* __restrict__ accA,
                                                      const int* __restrict__ accB,
                                                      const float* __restrict__ xag,
                                                      const float* __restrict__ s3,
                                                      float* __restrict__ out) {
  int m = blockIdx.x;
  float sm = s3[m];
  int4 a0 = ((const int4*)(accA + (long)m * 1024))[threadIdx.x];
  int4 a1 = ((const int4*)(accB + (long)m * 1024))[threadIdx.x];
  float4 xv = ((const float4*)(xag + (long)m * 1024))[threadIdx.x];
  float4 o;
  o.x = xv.x + sm * (float)(a0.x + a1.x);
  o.y = xv.y + sm * (float)(a0.y + a1.y);
  o.z = xv.z + sm * (float)(a0.z + a1.z);
  o.w = xv.w + sm * (float)(a0.w + a1.w);
  ((float4*)(out + (long)m * 1024))[threadIdx.x] = o;
}

// ============================================================================
// int8 GEMM, 256x256 tile, BK=128, 8 waves (2Mx4N), 16x16x64 MFMA.
// r3: r2 measured tile-time ~= MFMA + LDS (no pipe overlap; MfmaUtil 39%).
// Cause: reads issued in 12-read bursts (ph0/ph3) = 1152 cyc of LDS pipe per
// burst vs ~650 cyc MFMA per phase -> every other lgkm stalls. Fix:
//  - vmcnt wait for buf 1-p moved ph3 -> ph2 (only tile t+1's 8 glds are in
//    flight there, issued 3 phases ~2000 cyc earlier: pre-drained, T4-clean),
//    so next-tile reads can start 2 phases before first use.
//  - Flat issue rate 6 reads/wave/phase, each awaited exactly one full MFMA
//    phase after issue via counted lgkmcnt. Per-wave FIFO audit (steady state,
//    outstanding after each step):
//      entry ph0: [I2(6),I3(6)]=12 (a0,b0 of tile t, issued t-1.ph2/ph3)
//      ph0: +I0(b1(4),a1m0(2))=18; LGKM(6) drains I2,I3 -> a0,b0 ready; MFQ00
//      ph1: +I1(a1m1-3(6))=12;     LGKM(8) drains b1 -> MFQ01
//      ph2: VMC(0) [t+1 glds]; SBAR_B; +I2'(a0'm0-2)=14; LGKM(6) drains
//           a1m0+I1 -> a1 ready; MFQ10
//      ph3: SBAR_C [all waves' buf-p reads retired at their ph2 LGKM];
//           STAGE(t+2 -> buf p); +I3'(a0'm3,b0'(6))=12; MFQ11
//    48 reads/CU/phase = ~576 cyc LDS pipe < ~653 cyc MFMA -> continuous feed.
//  - Barriers 4 -> 2 per tile (only the two buffer-handoff ones); waves may
//    drift, per-wave counted waits stay exact (no cross-wave count deps).
//  - Last tile peeled (no staging/barriers; LGKM(6)/(8)/(0) closes counts).
//  - Rule 18: every inline s_waitcnt + each issue group ends in
//    sched_barrier(0). XOR swizzle (T2) + mt-fastest XCD mapping unchanged
//    (r2-verified: FETCH = A exactly once).
// mode 1: outh[m,n] = bf16(gelu(scale[m]*acc));  mode 2: iacc store.
// ============================================================================

#define LGKM(n) do { asm volatile("s_waitcnt lgkmcnt(" #n ")" ::: "memory"); \
                     __builtin_amdgcn_sched_barrier(0); } while (0)
#define VMC(n)  do { asm volatile("s_waitcnt vmcnt(" #n ")" ::: "memory");   \
                     __builtin_amdgcn_sched_barrier(0); } while (0)
#define SBAR    __builtin_amdgcn_s_barrier()
#define SCHED0  __builtin_amdgcn_sched_barrier(0)

#define RD16(P, O) (*(const v4i*)((P) + (O)))

// issue groups: 6 ds_read_b128 each (see FIFO audit above)
#define ISS_I0(BO) do { /* b1 first (LGKM(8) at ph1 counts on it), then a1m0 */\
  b1[0][0]=RD16(pB0,(BO)+4096);      b1[0][1]=RD16(pB1,(BO)+4096);            \
  b1[1][0]=RD16(pB0,(BO)+4096+2048); b1[1][1]=RD16(pB1,(BO)+4096+2048);       \
  SCHED0;                                                                     \
  a1[0][0]=RD16(pA0,(BO)+8192);      a1[0][1]=RD16(pA1,(BO)+8192);            \
  SCHED0; } while (0)

#define ISS_I1(BO) do {                                                       \
  a1[1][0]=RD16(pA0,(BO)+8192+2048); a1[1][1]=RD16(pA1,(BO)+8192+2048);       \
  a1[2][0]=RD16(pA0,(BO)+8192+4096); a1[2][1]=RD16(pA1,(BO)+8192+4096);       \
  a1[3][0]=RD16(pA0,(BO)+8192+6144); a1[3][1]=RD16(pA1,(BO)+8192+6144);       \
  SCHED0; } while (0)

#define ISS_I2(BO) do {                                                       \
  a0[0][0]=RD16(pA0,(BO));      a0[0][1]=RD16(pA1,(BO));                      \
  a0[1][0]=RD16(pA0,(BO)+2048); a0[1][1]=RD16(pA1,(BO)+2048);                 \
  a0[2][0]=RD16(pA0,(BO)+4096); a0[2][1]=RD16(pA1,(BO)+4096);                 \
  SCHED0; } while (0)

#define ISS_I3(BO) do {                                                       \
  a0[3][0]=RD16(pA0,(BO)+6144); a0[3][1]=RD16(pA1,(BO)+6144);                 \
  b0[0][0]=RD16(pB0,(BO));      b0[0][1]=RD16(pB1,(BO));                      \
  b0[1][0]=RD16(pB0,(BO)+2048); b0[1][1]=RD16(pB1,(BO)+2048);                 \
  SCHED0; } while (0)

// one C-quadrant (QM,QN): 16 MFMA, all-static acc indexing
#define MFQ(Af, Bf, QM, QN)                                                    \
  do {                                                                         \
    __builtin_amdgcn_s_setprio(1);                                             \
    _Pragma("unroll") for (int m2 = 0; m2 < 4; ++m2) {                         \
      _Pragma("unroll") for (int n2 = 0; n2 < 2; ++n2) {                       \
        acc[(QM)*4 + m2][(QN)*2 + n2] = __builtin_amdgcn_mfma_i32_16x16x64_i8( \
            Af[m2][0], Bf[n2][0], acc[(QM)*4 + m2][(QN)*2 + n2], 0, 0, 0);     \
        acc[(QM)*4 + m2][(QN)*2 + n2] = __builtin_amdgcn_mfma_i32_16x16x64_i8( \
            Af[m2][1], Bf[n2][1], acc[(QM)*4 + m2][(QN)*2 + n2], 0, 0, 0);     \
      }                                                                        \
    }                                                                          \
    __builtin_amdgcn_s_setprio(0);                                             \
  } while (0)

__global__ __launch_bounds__(512, 2) void gemm_i8_p(const signed char* __restrict__ A,
                                                    const signed char* __restrict__ Bw,
                                                    __hip_bfloat16* __restrict__ outh,
                                                    int* __restrict__ iacc0,
                                                    int* __restrict__ iacc1,
                                                    const float* __restrict__ scale,
                                                    int N, long K, int nt, int mode,
                                                    int nM, int nN) {
  __shared__ __align__(16) signed char lds[131072];  // A: [0,64K), B: [64K,128K)
  const int tid = threadIdx.x;
  const int lane = tid & 63;
  const int wave = tid >> 6;
  const int wm = wave >> 2, wn = wave & 3;  // 2x4 wave grid, 128x64 C per wave
  const int r15 = lane & 15, quad = lane >> 4, sw = lane & 7;

  // mt fastest (no XCD swizzle: same-mt => same XCD => A-panel L2 reuse)
  const int g = (int)blockIdx.x;
  const int mt = g % nM;
  const int rest = g / nM;
  const int ntl = rest % nN;
  const int z = rest / nN;
  const long m0 = (long)mt * 256, n0 = (long)ntl * 256;
  const signed char* Ab = A + m0 * K;
  const signed char* Bb = Bw + n0 * K;
  const long k0base = (long)z * nt * 128;

  // glds per-lane 32-bit global offsets (4 chunks; identical for A and B)
  unsigned voff[4];
#pragma unroll
  for (int i = 0; i < 4; ++i) {
    int c = wave * 64 + i * 512 + lane;
    int row = c >> 3;
    int blk = (c & 7) ^ (row & 7);  // pre-swizzled source column block
    voff[i] = (unsigned)row * (unsigned)K + (unsigned)(blk << 4);
  }

  // ds_read base pointers (k-slice 0/1 have different XOR'd column offsets)
  const signed char* pA0 = lds + (wm * 128 + r15) * 128 + ((quad ^ sw) << 4);
  const signed char* pA1 = lds + (wm * 128 + r15) * 128 + (((quad + 4) ^ sw) << 4);
  const signed char* pB0 = lds + 65536 + (wn * 64 + r15) * 128 + ((quad ^ sw) << 4);
  const signed char* pB1 = lds + 65536 + (wn * 64 + r15) * 128 + (((quad + 4) ^ sw) << 4);

  v4i a0[4][2], a1[4][2], b0[2][2], b1[2][2];
  v4i acc[8][4] = {};

#define STAGE(BO, KOFF)                                                        \
  _Pragma("unroll") for (int i = 0; i < 4; ++i) {                              \
    int cb = wave * 64 + i * 512;                                              \
    glds16(Ab + (KOFF) + voff[i], (void*)(lds + (BO) + cb * 16));              \
    glds16(Bb + (KOFF) + voff[i], (void*)(lds + 65536 + (BO) + cb * 16));      \
  }

  // ---- prologue: stage tiles 0,1; wait tile 0 (own 8 oldest); issue a0,b0 ----
  STAGE(0, k0base);
  STAGE(32768, k0base + 128);
  VMC(8);
  SBAR;
  ISS_I2(0);
  ISS_I3(0);

  for (int t = 0; t < nt - 1; ++t) {
    const int bo = (t & 1) << 15;
    const int bn = bo ^ 32768;
    // ph0: outstanding [I2(6),I3(6)]; +I0 -> 18; wait a0,b0
    ISS_I0(bo);
    LGKM(6);
    MFQ(a0, b0, 0, 0);
    // ph1: +I1 -> 12; wait b1 (leaves a1m0+I1 = 8)
    ISS_I1(bo);
    LGKM(8);
    MFQ(a0, b1, 0, 1);
    // ph2: t+1's glds (issued t-1.ph3, ~2000 cyc ago) -> buf bn readable
    VMC(0);
    SBAR;  // SBAR_B: all waves' glds for tile t+1 retired
    ISS_I2(bn);
    LGKM(6);  // drains a1m0+I1 -> a1 ready (leaves I2')
    MFQ(a1, b0, 1, 0);
    // ph3: all waves retired their buf-bo reads at their ph2 LGKM
    SBAR;  // SBAR_C: buf bo free to overwrite
    if (t + 2 < nt) { STAGE(bo, k0base + (long)(t + 2) * 128); }
    ISS_I3(bn);
    MFQ(a1, b1, 1, 1);
  }

  // ---- peeled last tile (no staging, no barriers; close out counts) ----
  {
    const int bo = ((nt - 1) & 1) << 15;
    ISS_I0(bo);
    LGKM(6);
    MFQ(a0, b0, 0, 0);
    ISS_I1(bo);
    LGKM(8);
    MFQ(a0, b1, 0, 1);
    LGKM(0);
    MFQ(a1, b0, 1, 0);
    MFQ(a1, b1, 1, 1);
  }

  // ---- epilogue: C layout col=lane&15, row=quad*4+reg (harness-verified) ----
  if (mode == 2) {
    int* iacc = z ? iacc1 : iacc0;
#pragma unroll
    for (int mi = 0; mi < 8; ++mi) {
#pragma unroll
      for (int r = 0; r < 4; ++r) {
        long m = m0 + wm * 128 + mi * 16 + quad * 4 + r;
        int* arow = iacc + m * N;
#pragma unroll
        for (int ni = 0; ni < 4; ++ni)
          arow[n0 + wn * 64 + ni * 16 + r15] = acc[mi][ni][r];
      }
    }
  } else {
#pragma unroll
    for (int mi = 0; mi < 8; ++mi) {
#pragma unroll
      for (int r = 0; r < 4; ++r) {
        long m = m0 + wm * 128 + mi * 16 + quad * 4 + r;
        float sm = scale[m];
        __hip_bfloat16* orow = outh + m * N;
#pragma unroll
        for (int ni = 0; ni < 4; ++ni) {
          float v = sm * (float)acc[mi][ni][r];
          orow[n0 + wn * 64 + ni * 16 + r15] =
              __float2bfloat16(0.5f * v * (1.f + erff(v * 0.70710678118654752f)));
        }
      }
    }
  }
}

extern "C" void kernel_launch(void* const* d_in, const int* in_sizes, int n_in,
                              void* d_out, int out_size, void* d_ws, size_t ws_size,
                              hipStream_t stream) {
  const float* x    = (const float*)d_in[0];
  const float* ln1w = (const float*)d_in[1];
  const float* ln1b = (const float*)d_in[2];
  const float* ln2w = (const float*)d_in[3];
  const float* ln2b = (const float*)d_in[4];
  const float* Wg   = (const float*)d_in[5];
  const float* W1   = (const float*)d_in[6];
  const float* W2   = (const float*)d_in[7];
  const int* is0    = (const int*)d_in[8];
  const int* is1    = (const int*)d_in[9];
  const int* iv     = (const int*)d_in[10];
  float* out = (float*)d_out;

  // workspace layout, peak ~234 MB (unchanged from verified layout):
  char* ws = (char*)d_ws;
  float* sums = (float*)ws;                                   // 3 floats (+pad)
  signed char* t_g = (signed char*)(ws + 256);                // 15,728,640
  signed char* t_1 = t_g + 15728640;                          //  4,194,304
  signed char* t_2 = t_1 + 4194304;                           //  4,194,304
  float* rowmax1 = (float*)(t_2 + 4194304);                   // 32 KB
  float* s1  = rowmax1 + 8192;
  float* s2  = s1 + 8192;
  float* s3  = s2 + 8192;
  float* xag = s3 + 8192;
  int* acc1b = (int*)xag;
  signed char* hq = (signed char*)(xag + 8388608);            //  8.39 MB
  float* xn = (float*)(hq + 8388608);
  int* acc1a = (int*)xn;
  signed char* q3 = (signed char*)xn;
  signed char* Aq = (signed char*)(xn + 8388608);
  unsigned short* gg = (unsigned short*)Aq;
  int* acc3a = (int*)Aq;
  int* acc3b = acc3a + 8192l * 1024;

  hipMemsetAsync(sums, 0, 64, stream);
  absum3_kernel<<<1024, 256, 0, stream>>>(Wg, W1, W2, sums);
  ternarize3_kernel<<<2048, 256, 0, stream>>>(Wg, W1, W2, t_g, t_1, t_2, sums);
  ln_rowmax_kernel<<<8192, 256, 0, stream>>>(x, ln1w, ln1b, xn, rowmax1);
  quantA_kernel<<<8192, 256, 0, stream>>>(xn, is0, is1, iv, rowmax1, sums, Aq, s1);
  // GEMM1: M=8192 N=1024 K=15360, split-K=2 -> 32*4*2 = 256 blocks (1/CU)
  gemm_i8_p<<<256, 512, 0, stream>>>(Aq, t_g, nullptr, acc1a, acc1b, nullptr,
                                     1024, 15360L, 60, 2, 32, 4);
  ln_quant_acc_kernel<<<8192, 256, 0, stream>>>(acc1a, acc1b, x, s1, ln2w, ln2b, xag, hq, s2,
                                                &sums[1], 1.f / 4194304.f);
  // GEMM2: M=8192 N=4096 K=1024, gelu -> bf16, 32*16 = 512 blocks
  gemm_i8_p<<<512, 512, 0, stream>>>(hq, t_1, (__hip_bfloat16*)gg, nullptr, nullptr,
                                     s2, 4096, 1024L, 8, 1, 32, 16);
  rowquant4k_kernel<<<8192, 256, 0, stream>>>(gg, q3, s3, &sums[2], 1.f / 4194304.f);
  // GEMM3: M=8192 N=1024 K=4096, split-K=2 -> 256 blocks
  gemm_i8_p<<<256, 512, 0, stream>>>(q3, t_2, nullptr, acc3a, acc3b, nullptr,
                                     1024, 4096L, 16, 2, 32, 4);
  reduce3_kernel<<<8192, 256, 0, stream>>>(acc3a, acc3b, xag, s3, out);
}

// Round 5
// 527.325 us; speedup vs baseline: 1.0279x; 1.0279x over previous
//
#include <hip/hip_runtime.h>
#include <hip/hip_bf16.h>
#include <math.h>
#include <stdint.h>

#define EPS 1e-5f

typedef int v4i __attribute__((ext_vector_type(4)));

__device__ __forceinline__ void glds16(const void* g, void* l) {
  __builtin_amdgcn_global_load_lds(
      (const __attribute__((address_space(1))) void*)g,
      (__attribute__((address_space(3))) void*)l, 16, 0, 0);
}

__device__ __forceinline__ signed char q8(float f, float xs) {
  float r = rintf(f * xs);
  r = fminf(fmaxf(r, -128.f), 127.f);
  return (signed char)(int)r;
}

__device__ __forceinline__ float bf2f(unsigned short h) {
  return __builtin_bit_cast(float, (unsigned)h << 16);
}

// ---------------- merged weight abs-sum (3 tensors, 1 launch) ----------------
__global__ __launch_bounds__(256) void absum3_kernel(const float* __restrict__ Wg,
                                                     const float* __restrict__ W1,
                                                     const float* __restrict__ W2,
                                                     float* __restrict__ out) {
  int blk = blockIdx.x;
  const float* w; long n4; float* o; long lb; long nb;
  if (blk < 512)      { w = Wg; n4 = 3932160; o = &out[0]; lb = blk;       nb = 512; }
  else if (blk < 768) { w = W1; n4 = 1048576; o = &out[1]; lb = blk - 512; nb = 256; }
  else                { w = W2; n4 = 1048576; o = &out[2]; lb = blk - 768; nb = 256; }
  const float4* w4 = (const float4*)w;
  float s = 0.f;
  for (long i = lb * 256 + threadIdx.x; i < n4; i += nb * 256) {
    float4 v = w4[i];
    s += fabsf(v.x) + fabsf(v.y) + fabsf(v.z) + fabsf(v.w);
  }
  for (int off = 32; off; off >>= 1) s += __shfl_down(s, off);
  __shared__ float sb[4];
  int lane = threadIdx.x & 63, wid = threadIdx.x >> 6;
  if (lane == 0) sb[wid] = s;
  __syncthreads();
  if (threadIdx.x == 0) atomicAdd(o, sb[0] + sb[1] + sb[2] + sb[3]);
}

// ---------------- merged ternarize (3 tensors, 1 launch) ----------------
__global__ __launch_bounds__(256) void ternarize3_kernel(const float* __restrict__ Wg,
                                                         const float* __restrict__ W1,
                                                         const float* __restrict__ W2,
                                                         signed char* __restrict__ tg,
                                                         signed char* __restrict__ t1,
                                                         signed char* __restrict__ t2,
                                                         const float* __restrict__ sums) {
  int blk = blockIdx.x;
  const float* w; signed char* t; long n4; float ws; long lb; long nb;
  if (blk < 1024) {
    w = Wg; t = tg; n4 = 3932160; ws = sums[0] * (1.f / 15728640.f) + EPS; lb = blk; nb = 1024;
  } else if (blk < 1536) {
    w = W1; t = t1; n4 = 1048576; ws = sums[1] * (1.f / 4194304.f) + EPS; lb = blk - 1024; nb = 512;
  } else {
    w = W2; t = t2; n4 = 1048576; ws = sums[2] * (1.f / 4194304.f) + EPS; lb = blk - 1536; nb = 512;
  }
  const float4* w4 = (const float4*)w;
  char4* t4 = (char4*)t;
  for (long i = lb * 256 + threadIdx.x; i < n4; i += nb * 256) {
    float4 v = w4[i];
    char4 c;
    c.x = (signed char)(int)fminf(fmaxf(rintf(v.x / ws), -1.f), 1.f);
    c.y = (signed char)(int)fminf(fmaxf(rintf(v.y / ws), -1.f), 1.f);
    c.z = (signed char)(int)fminf(fmaxf(rintf(v.z / ws), -1.f), 1.f);
    c.w = (signed char)(int)fminf(fmaxf(rintf(v.w / ws), -1.f), 1.f);
    t4[i] = c;
  }
}

// ---------------- LN1: write xn fp32 + per-row absmax ----------------
__global__ __launch_bounds__(256) void ln_rowmax_kernel(const float* __restrict__ x,
                                                        const float* __restrict__ w,
                                                        const float* __restrict__ b,
                                                        float* __restrict__ xn,
                                                        float* __restrict__ rowmax) {
  int m = blockIdx.x;
  int tid = threadIdx.x, lane = tid & 63, wid = tid >> 6;
  __shared__ float sb[4];
  float4 v = ((const float4*)(x + (long)m * 1024))[tid];
  float s = v.x + v.y + v.z + v.w;
  for (int off = 32; off; off >>= 1) s += __shfl_down(s, off);
  if (lane == 0) sb[wid] = s;
  __syncthreads();
  float mean = (sb[0] + sb[1] + sb[2] + sb[3]) * (1.f / 1024.f);
  __syncthreads();
  float dx = v.x - mean, dy = v.y - mean, dz = v.z - mean, dw = v.w - mean;
  float ss = dx * dx + dy * dy + dz * dz + dw * dw;
  for (int off = 32; off; off >>= 1) ss += __shfl_down(ss, off);
  if (lane == 0) sb[wid] = ss;
  __syncthreads();
  float rstd = rsqrtf((sb[0] + sb[1] + sb[2] + sb[3]) * (1.f / 1024.f) + EPS);
  __syncthreads();
  float4 wv = ((const float4*)w)[tid];
  float4 bv = ((const float4*)b)[tid];
  float4 o;
  o.x = dx * rstd * wv.x + bv.x;
  o.y = dy * rstd * wv.y + bv.y;
  o.z = dz * rstd * wv.z + bv.z;
  o.w = dw * rstd * wv.w + bv.w;
  ((float4*)(xn + (long)m * 1024))[tid] = o;
  float mx = fmaxf(fmaxf(fabsf(o.x), fabsf(o.y)), fmaxf(fabsf(o.z), fabsf(o.w)));
  for (int off = 32; off; off >>= 1) mx = fmaxf(mx, __shfl_down(mx, off));
  if (lane == 0) sb[wid] = mx;
  __syncthreads();
  if (tid == 0) rowmax[m] = fmaxf(fmaxf(sb[0], sb[1]), fmaxf(sb[2], sb[3]));
}

// ---------------- quantA: per-dest-row combined scale + gather-quantize ----------------
__global__ __launch_bounds__(256) void quantA_kernel(const float* __restrict__ xn,
                                                     const int* __restrict__ is0,
                                                     const int* __restrict__ is1,
                                                     const int* __restrict__ iv,
                                                     const float* __restrict__ rowmax,
                                                     const float* __restrict__ sums,
                                                     signed char* __restrict__ Aq,
                                                     float* __restrict__ s1) {
  int m = blockIdx.x;
  int b = m >> 8, l = m & 255;
  const float* rm = rowmax + b * 256;
  int src[15];
  src[0] = l;
#pragma unroll
  for (int j = 0; j < 3; ++j) { src[1 + j] = is0[l * 3 + j]; src[4 + j] = is1[l * 3 + j]; }
#pragma unroll
  for (int j = 0; j < 8; ++j) src[7 + j] = iv[l * 8 + j];
  float c = EPS;
#pragma unroll
  for (int sl = 0; sl < 15; ++sl) c = fmaxf(c, rm[src[sl]]);
  float xs = 127.f / c;
  if (threadIdx.x == 0) s1[m] = (sums[0] * (1.f / 15728640.f) + EPS) * c * (1.f / 127.f);
#pragma unroll
  for (int sl = 0; sl < 15; ++sl) {
    float4 v = ((const float4*)(xn + ((long)(b << 8) + src[sl]) * 1024))[threadIdx.x];
    char4 cc;
    cc.x = q8(v.x, xs); cc.y = q8(v.y, xs); cc.z = q8(v.z, xs); cc.w = q8(v.w, xs);
    *(char4*)&Aq[(long)m * 15360 + sl * 1024 + threadIdx.x * 4] = cc;
  }
}

// ---------------- fused: xag = x + s1*(acc0+acc1); LN2; quantize to int8 ----------------
__global__ __launch_bounds__(256) void ln_quant_acc_kernel(const int* __restrict__ accA,
                                                           const int* accB,
                                                           const float* __restrict__ x,
                                                           const float* __restrict__ s1,
                                                           const float* __restrict__ w,
                                                           const float* __restrict__ bb,
                                                           float* xag,
                                                           signed char* __restrict__ q,
                                                           float* __restrict__ srow,
                                                           const float* __restrict__ sum_ptr,
                                                           float inv_n) {
  int m = blockIdx.x;
  int tid = threadIdx.x, lane = tid & 63, wid = tid >> 6;
  __shared__ float sb[4];
  float sm = s1[m];
  int4 a0 = ((const int4*)(accA + (long)m * 1024))[tid];
  int4 a1 = ((const int4*)(accB + (long)m * 1024))[tid];
  float4 xv = ((const float4*)(x + (long)m * 1024))[tid];
  float4 v;
  v.x = xv.x + sm * (float)(a0.x + a1.x);
  v.y = xv.y + sm * (float)(a0.y + a1.y);
  v.z = xv.z + sm * (float)(a0.z + a1.z);
  v.w = xv.w + sm * (float)(a0.w + a1.w);
  ((float4*)(xag + (long)m * 1024))[tid] = v;
  float s = v.x + v.y + v.z + v.w;
  for (int off = 32; off; off >>= 1) s += __shfl_down(s, off);
  if (lane == 0) sb[wid] = s;
  __syncthreads();
  float mean = (sb[0] + sb[1] + sb[2] + sb[3]) * (1.f / 1024.f);
  __syncthreads();
  float dx = v.x - mean, dy = v.y - mean, dz = v.z - mean, dw = v.w - mean;
  float ss = dx * dx + dy * dy + dz * dz + dw * dw;
  for (int off = 32; off; off >>= 1) ss += __shfl_down(ss, off);
  if (lane == 0) sb[wid] = ss;
  __syncthreads();
  float rstd = rsqrtf((sb[0] + sb[1] + sb[2] + sb[3]) * (1.f / 1024.f) + EPS);
  __syncthreads();
  float4 wv = ((const float4*)w)[tid];
  float4 bv = ((const float4*)bb)[tid];
  float nx = dx * rstd * wv.x + bv.x;
  float ny = dy * rstd * wv.y + bv.y;
  float nz = dz * rstd * wv.z + bv.z;
  float nw = dw * rstd * wv.w + bv.w;
  float mx = fmaxf(fmaxf(fabsf(nx), fabsf(ny)), fmaxf(fabsf(nz), fabsf(nw)));
  for (int off = 32; off; off >>= 1) mx = fmaxf(mx, __shfl_down(mx, off));
  if (lane == 0) sb[wid] = mx;
  __syncthreads();
  float rmax = fmaxf(fmaxf(fmaxf(sb[0], sb[1]), fmaxf(sb[2], sb[3])), EPS);
  float xs = 127.f / rmax;
  char4 c;
  c.x = q8(nx, xs); c.y = q8(ny, xs); c.z = q8(nz, xs); c.w = q8(nw, xs);
  *(char4*)&q[(long)m * 1024 + tid * 4] = c;
  if (tid == 0) srow[m] = (sum_ptr[0] * inv_n + EPS) * rmax * (1.f / 127.f);
}

// ---------------- row quantize [8192,4096] bf16 -> int8 ----------------
__global__ __launch_bounds__(256) void rowquant4k_kernel(const unsigned short* __restrict__ g,
                                                         signed char* __restrict__ q,
                                                         float* __restrict__ srow,
                                                         const float* __restrict__ sum_ptr,
                                                         float inv_n) {
  int m = blockIdx.x;
  int tid = threadIdx.x, lane = tid & 63, wid = tid >> 6;
  __shared__ float sb[4];
  const uint4* gr = (const uint4*)(g + (long)m * 4096);  // 16B = 8 bf16
  float f[16];
  float mx = 0.f;
#pragma unroll
  for (int i = 0; i < 2; ++i) {
    uint4 u = gr[tid + i * 256];
    unsigned uu[4] = {u.x, u.y, u.z, u.w};
#pragma unroll
    for (int j = 0; j < 4; ++j) {
      float lo = bf2f((unsigned short)(uu[j] & 0xFFFF));
      float hi = bf2f((unsigned short)(uu[j] >> 16));
      f[i * 8 + j * 2] = lo;
      f[i * 8 + j * 2 + 1] = hi;
      mx = fmaxf(mx, fmaxf(fabsf(lo), fabsf(hi)));
    }
  }
  for (int off = 32; off; off >>= 1) mx = fmaxf(mx, __shfl_down(mx, off));
  if (lane == 0) sb[wid] = mx;
  __syncthreads();
  float rmax = fmaxf(fmaxf(fmaxf(sb[0], sb[1]), fmaxf(sb[2], sb[3])), EPS);
  float xs = 127.f / rmax;
#pragma unroll
  for (int i = 0; i < 2; ++i) {
    char4 c0, c1;
    c0.x = q8(f[i * 8 + 0], xs); c0.y = q8(f[i * 8 + 1], xs);
    c0.z = q8(f[i * 8 + 2], xs); c0.w = q8(f[i * 8 + 3], xs);
    c1.x = q8(f[i * 8 + 4], xs); c1.y = q8(f[i * 8 + 5], xs);
    c1.z = q8(f[i * 8 + 6], xs); c1.w = q8(f[i * 8 + 7], xs);
    long base = (long)m * 4096 + (tid + i * 256) * 8;
    *(char4*)&q[base] = c0;
    *(char4*)&q[base + 4] = c1;
  }
  if (tid == 0) srow[m] = (sum_ptr[0] * inv_n + EPS) * rmax * (1.f / 127.f);
}

// ---------------- final residual: out = xag + s3*(acc0+acc1) ----------------
__global__ __launch_bounds__(256) void reduce3_kernel(const int* __restrict__ accA,
                                                      const int* __restrict__ accB,
                                                      const float* __restrict__ xag,
                                                      const float* __restrict__ s3,
                                                      float* __restrict__ out) {
  int m = blockIdx.x;
  float sm = s3[m];
  int4 a0 = ((const int4*)(accA + (long)m * 1024))[threadIdx.x];
  int4 a1 = ((const int4*)(accB + (long)m * 1024))[threadIdx.x];
  float4 xv = ((const float4*)(xag + (long)m * 1024))[threadIdx.x];
  float4 o;
  o.x = xv.x + sm * (float)(a0.x + a1.x);
  o.y = xv.y + sm * (float)(a0.y + a1.y);
  o.z = xv.z + sm * (float)(a0.z + a1.z);
  o.w = xv.w + sm * (float)(a0.w + a1.w);
  ((float4*)(out + (long)m * 1024))[threadIdx.x] = o;
}

// ============================================================================
// int8 GEMM, 256x256 tile, BK=128, 8 waves (2Mx4N), 16x16x64 MFMA.
// r5 = r4 (m201 8-phase rhythm) with the tail-drain race FIXED:
//   r4 BUG: at t = nt-2, ph3 stages nothing (t+2==nt), so the vmcnt queue
//   holds ONLY tile-(nt-1)'s 8 glds; VMC(6) retired just 2 of them and
//   ph0(nt-1) read up to 6 unlanded chunks -> absmax 0.95. The "VMC(6)
//   drains t+1's 8" invariant requires ph3 to have issued 6 new glds.
//   FIX: key the counted wait on (t+2<nt) -- VMC(6) only when 6 new glds
//   were just staged, else VMC(0).
// Schedule per phase: { reads_p ; (stage) ; SBAR ; lgkmcnt(0) ; setprio(1) ;
// 16 MFMA ; setprio(0) ; SBAR }; phases read (a0+b0 | b1 | a1 | none);
// stage-for-(t+2): 6 glds in read-free ph3 + tail 2 glds at ph0(t+1).
// Producer/consumer audit (steady state):
//  - buf(1-p) [tile t+1]: 6 glds @ph3(t-1) + 2 @ph0(t); VMC(6) @ph3(t)
//    (queue = t+1's 8 + t+2's 6) drains t+1's 8; SBAR -> ph0(t+1) reads safe.
//  - buf p overwrite @ph3(t): all waves' p-reads retired at their ph2
//    lgkmcnt(0) before ph2's trailing SBAR -> safe.
//  - tail t=nt-2: no stage at ph3 -> VMC(0) drains t+1's 8 fully. t=nt-1:
//    VMC(0) trivial.
// Reads dedup'd: 24 ds_read_b128/wave/tile (a0:8, b0:4, b1:4, a1:8).
// XOR swizzle (T2) + mt-fastest XCD mapping unchanged (FETCH=A-once, r2).
// mode 1: outh[m,n] = bf16(gelu(scale[m]*acc));  mode 2: iacc store.
// ============================================================================

#define LGKM(n) do { asm volatile("s_waitcnt lgkmcnt(" #n ")" ::: "memory"); \
                     __builtin_amdgcn_sched_barrier(0); } while (0)
#define VMC(n)  do { asm volatile("s_waitcnt vmcnt(" #n ")" ::: "memory");   \
                     __builtin_amdgcn_sched_barrier(0); } while (0)
#define SBAR    __builtin_amdgcn_s_barrier()
#define SCHED0  __builtin_amdgcn_sched_barrier(0)

#define RD16(P, O) (*(const v4i*)((P) + (O)))

// read one A-half (8 ds_read_b128) / one B-half (4 ds_read_b128)
#define RDA(arr, BO, QMOFS)                                                    \
  do { _Pragma("unroll") for (int m2 = 0; m2 < 4; ++m2) {                      \
    arr[m2][0] = RD16(pA0, (BO) + (QMOFS) + m2 * 2048);                        \
    arr[m2][1] = RD16(pA1, (BO) + (QMOFS) + m2 * 2048);                        \
  } SCHED0; } while (0)
#define RDB(arr, BO, QNOFS)                                                    \
  do { _Pragma("unroll") for (int n2 = 0; n2 < 2; ++n2) {                      \
    arr[n2][0] = RD16(pB0, (BO) + (QNOFS) + n2 * 2048);                        \
    arr[n2][1] = RD16(pB1, (BO) + (QNOFS) + n2 * 2048);                        \
  } SCHED0; } while (0)

// one C-quadrant (QM,QN): 16 MFMA, all-static acc indexing
#define MFQ(Af, Bf, QM, QN)                                                    \
  do {                                                                         \
    __builtin_amdgcn_s_setprio(1);                                             \
    _Pragma("unroll") for (int m2 = 0; m2 < 4; ++m2) {                         \
      _Pragma("unroll") for (int n2 = 0; n2 < 2; ++n2) {                       \
        acc[(QM)*4 + m2][(QN)*2 + n2] = __builtin_amdgcn_mfma_i32_16x16x64_i8( \
            Af[m2][0], Bf[n2][0], acc[(QM)*4 + m2][(QN)*2 + n2], 0, 0, 0);     \
        acc[(QM)*4 + m2][(QN)*2 + n2] = __builtin_amdgcn_mfma_i32_16x16x64_i8( \
            Af[m2][1], Bf[n2][1], acc[(QM)*4 + m2][(QN)*2 + n2], 0, 0, 0);     \
      }                                                                        \
    }                                                                          \
    __builtin_amdgcn_s_setprio(0);                                             \
  } while (0)

__global__ __launch_bounds__(512, 2) void gemm_i8_p(const signed char* __restrict__ A,
                                                    const signed char* __restrict__ Bw,
                                                    __hip_bfloat16* __restrict__ outh,
                                                    int* __restrict__ iacc0,
                                                    int* __restrict__ iacc1,
                                                    const float* __restrict__ scale,
                                                    int N, long K, int nt, int mode,
                                                    int nM, int nN) {
  __shared__ __align__(16) signed char lds[131072];  // A: [0,64K), B: [64K,128K)
  const int tid = threadIdx.x;
  const int lane = tid & 63;
  const int wave = tid >> 6;
  const int wm = wave >> 2, wn = wave & 3;  // 2x4 wave grid, 128x64 C per wave
  const int r15 = lane & 15, quad = lane >> 4, sw = lane & 7;

  // mt fastest (no XCD swizzle: same-mt => same XCD => A-panel L2 reuse)
  const int g = (int)blockIdx.x;
  const int mt = g % nM;
  const int rest = g / nM;
  const int ntl = rest % nN;
  const int z = rest / nN;
  const long m0 = (long)mt * 256, n0 = (long)ntl * 256;
  const signed char* Ab = A + m0 * K;
  const signed char* Bb = Bw + n0 * K;
  const long k0base = (long)z * nt * 128;

  // glds per-lane 32-bit global offsets (4 chunks; identical for A and B)
  unsigned voff[4];
#pragma unroll
  for (int i = 0; i < 4; ++i) {
    int c = wave * 64 + i * 512 + lane;
    int row = c >> 3;
    int blk = (c & 7) ^ (row & 7);  // pre-swizzled source column block
    voff[i] = (unsigned)row * (unsigned)K + (unsigned)(blk << 4);
  }

  // ds_read base pointers (k-slice 0/1 have different XOR'd column offsets)
  const signed char* pA0 = lds + (wm * 128 + r15) * 128 + ((quad ^ sw) << 4);
  const signed char* pA1 = lds + (wm * 128 + r15) * 128 + (((quad + 4) ^ sw) << 4);
  const signed char* pB0 = lds + 65536 + (wn * 64 + r15) * 128 + ((quad ^ sw) << 4);
  const signed char* pB1 = lds + 65536 + (wn * 64 + r15) * 128 + (((quad + 4) ^ sw) << 4);

  v4i a0[4][2], a1[4][2], b0[2][2], b1[2][2];
  v4i acc[8][4] = {};

  // stage pair i: one A-chunk + one B-chunk (2 glds, 2 KiB total per wave)
#define STAGE_PAIR(BO, KOFF, i)                                                \
  do {                                                                         \
    int cb = wave * 64 + (i) * 512;                                            \
    glds16(Ab + (KOFF) + voff[i], (void*)(lds + (BO) + cb * 16));              \
    glds16(Bb + (KOFF) + voff[i], (void*)(lds + 65536 + (BO) + cb * 16));      \
  } while (0)

  // ---- prologue: tile0 fully (8), tile1 partial (6); wait tile0; SBAR ----
  STAGE_PAIR(0, k0base, 0);
  STAGE_PAIR(0, k0base, 1);
  STAGE_PAIR(0, k0base, 2);
  STAGE_PAIR(0, k0base, 3);
  if (nt > 1) {
    STAGE_PAIR(32768, k0base + 128, 0);
    STAGE_PAIR(32768, k0base + 128, 1);
    STAGE_PAIR(32768, k0base + 128, 2);
    VMC(6);  // drains tile0's 8 (leaves tile1's 6)
  } else {
    VMC(0);
  }
  SBAR;

  for (int t = 0; t < nt; ++t) {
    const int bo = (t & 1) << 15;
    const int bn = bo ^ 32768;
    // ---- ph0: tail-stage t+1; reads a0,b0; SBAR; lgkm(0); MFQ00; SBAR ----
    if (t + 1 < nt) { STAGE_PAIR(bn, k0base + (long)(t + 1) * 128, 3); }
    RDA(a0, bo, 0);
    RDB(b0, bo, 0);
    SBAR;
    LGKM(0);
    MFQ(a0, b0, 0, 0);
    SBAR;
    // ---- ph1: reads b1; SBAR; lgkm(0); MFQ01; SBAR ----
    RDB(b1, bo, 4096);
    SBAR;
    LGKM(0);
    MFQ(a0, b1, 0, 1);
    SBAR;
    // ---- ph2: reads a1; SBAR; lgkm(0); MFQ10; SBAR ----
    RDA(a1, bo, 8192);
    SBAR;
    LGKM(0);
    MFQ(a1, b0, 1, 0);
    SBAR;  // after this: all waves' buf-p reads retired -> p overwrite-safe
    // ---- ph3 (read-free): stage 6 for t+2 into p; MFQ11; counted wait ----
    if (t + 2 < nt) {
      long kN2 = k0base + (long)(t + 2) * 128;
      STAGE_PAIR(bo, kN2, 0);
      STAGE_PAIR(bo, kN2, 1);
      STAGE_PAIR(bo, kN2, 2);
    }
    SBAR;
    MFQ(a1, b1, 1, 1);
    // r5 FIX: VMC(6) is only valid when ph3 just issued 6 new glds (queue =
    // t+1's 8 + t+2's 6). At t==nt-2 nothing was staged (queue = t+1's 8
    // only) -> VMC(6) would leave 6 of t+1's loads in flight while ph0(t+1)
    // reads them (the r4 race). Drain fully instead.
    if (t + 2 < nt) { VMC(6); }
    else           { VMC(0); }
    SBAR;
  }

  // ---- epilogue: C layout col=lane&15, row=quad*4+reg (harness-verified) ----
  if (mode == 2) {
    int* iacc = z ? iacc1 : iacc0;
#pragma unroll
    for (int mi = 0; mi < 8; ++mi) {
#pragma unroll
      for (int r = 0; r < 4; ++r) {
        long m = m0 + wm * 128 + mi * 16 + quad * 4 + r;
        int* arow = iacc + m * N;
#pragma unroll
        for (int ni = 0; ni < 4; ++ni)
          arow[n0 + wn * 64 + ni * 16 + r15] = acc[mi][ni][r];
      }
    }
  } else {
#pragma unroll
    for (int mi = 0; mi < 8; ++mi) {
#pragma unroll
      for (int r = 0; r < 4; ++r) {
        long m = m0 + wm * 128 + mi * 16 + quad * 4 + r;
        float sm = scale[m];
        __hip_bfloat16* orow = outh + m * N;
#pragma unroll
        for (int ni = 0; ni < 4; ++ni) {
          float v = sm * (float)acc[mi][ni][r];
          orow[n0 + wn * 64 + ni * 16 + r15] =
              __float2bfloat16(0.5f * v * (1.f + erff(v * 0.70710678118654752f)));
        }
      }
    }
  }
}

extern "C" void kernel_launch(void* const* d_in, const int* in_sizes, int n_in,
                              void* d_out, int out_size, void* d_ws, size_t ws_size,
                              hipStream_t stream) {
  const float* x    = (const float*)d_in[0];
  const float* ln1w = (const float*)d_in[1];
  const float* ln1b = (const float*)d_in[2];
  const float* ln2w = (const float*)d_in[3];
  const float* ln2b = (const float*)d_in[4];
  const float* Wg   = (const float*)d_in[5];
  const float* W1   = (const float*)d_in[6];
  const float* W2   = (const float*)d_in[7];
  const int* is0    = (const int*)d_in[8];
  const int* is1    = (const int*)d_in[9];
  const int* iv     = (const int*)d_in[10];
  float* out = (float*)d_out;

  // workspace layout, peak ~234 MB (unchanged from verified layout):
  char* ws = (char*)d_ws;
  float* sums = (float*)ws;                                   // 3 floats (+pad)
  signed char* t_g = (signed char*)(ws + 256);                // 15,728,640
  signed char* t_1 = t_g + 15728640;                          //  4,194,304
  signed char* t_2 = t_1 + 4194304;                           //  4,194,304
  float* rowmax1 = (float*)(t_2 + 4194304);                   // 32 KB
  float* s1  = rowmax1 + 8192;
  float* s2  = s1 + 8192;
  float* s3  = s2 + 8192;
  float* xag = s3 + 8192;
  int* acc1b = (int*)xag;
  signed char* hq = (signed char*)(xag + 8388608);            //  8.39 MB
  float* xn = (float*)(hq + 8388608);
  int* acc1a = (int*)xn;
  signed char* q3 = (signed char*)xn;
  signed char* Aq = (signed char*)(xn + 8388608);
  unsigned short* gg = (unsigned short*)Aq;
  int* acc3a = (int*)Aq;
  int* acc3b = acc3a + 8192l * 1024;

  hipMemsetAsync(sums, 0, 64, stream);
  absum3_kernel<<<1024, 256, 0, stream>>>(Wg, W1, W2, sums);
  ternarize3_kernel<<<2048, 256, 0, stream>>>(Wg, W1, W2, t_g, t_1, t_2, sums);
  ln_rowmax_kernel<<<8192, 256, 0, stream>>>(x, ln1w, ln1b, xn, rowmax1);
  quantA_kernel<<<8192, 256, 0, stream>>>(xn, is0, is1, iv, rowmax1, sums, Aq, s1);
  // GEMM1: M=8192 N=1024 K=15360, split-K=2 -> 32*4*2 = 256 blocks (1/CU)
  gemm_i8_p<<<256, 512, 0, stream>>>(Aq, t_g, nullptr, acc1a, acc1b, nullptr,
                                     1024, 15360L, 60, 2, 32, 4);
  ln_quant_acc_kernel<<<8192, 256, 0, stream>>>(acc1a, acc1b, x, s1, ln2w, ln2b, xag, hq, s2,
                                                &sums[1], 1.f / 4194304.f);
  // GEMM2: M=8192 N=4096 K=1024, gelu -> bf16, 32*16 = 512 blocks
  gemm_i8_p<<<512, 512, 0, stream>>>(hq, t_1, (__hip_bfloat16*)gg, nullptr, nullptr,
                                     s2, 4096, 1024L, 8, 1, 32, 16);
  rowquant4k_kernel<<<8192, 256, 0, stream>>>(gg, q3, s3, &sums[2], 1.f / 4194304.f);
  // GEMM3: M=8192 N=1024 K=4096, split-K=2 -> 256 blocks
  gemm_i8_p<<<256, 512, 0, stream>>>(q3, t_2, nullptr, acc3a, acc3b, nullptr,
                                     1024, 4096L, 16, 2, 32, 4);
  reduce3_kernel<<<8192, 256, 0, stream>>>(acc3a, acc3b, xag, s3, out);
}

// Round 6
// 521.360 us; speedup vs baseline: 1.0396x; 1.0114x over previous
//
#include <hip/hip_runtime.h>
#include <hip/hip_bf16.h>
#include <math.h>
#include <stdint.h>

#define EPS 1e-5f

typedef int v4i __attribute__((ext_vector_type(4)));

__device__ __forceinline__ void glds16(const void* g, void* l) {
  __builtin_amdgcn_global_load_lds(
      (const __attribute__((address_space(1))) void*)g,
      (__attribute__((address_space(3))) void*)l, 16, 0, 0);
}

__device__ __forceinline__ signed char q8(float f, float xs) {
  float r = rintf(f * xs);
  r = fminf(fmaxf(r, -128.f), 127.f);
  return (signed char)(int)r;
}

__device__ __forceinline__ float bf2f(unsigned short h) {
  return __builtin_bit_cast(float, (unsigned)h << 16);
}

// gelu via A&S 7.1.26 erf approx (max err 1.5e-7): ~13 VALU inst vs ~40+ for
// libm erff. erf(x) = 1 - poly(t)*exp(-x^2), t = 1/(1+p|x|), sign-restored.
__device__ __forceinline__ float gelu_f(float v) {
  float x = v * 0.70710678118654752f;
  float ax = fabsf(x);
  float t = __builtin_amdgcn_rcpf(__builtin_fmaf(0.3275911f, ax, 1.f));
  float poly = t * __builtin_fmaf(
                   t, __builtin_fmaf(
                          t, __builtin_fmaf(
                                 t, __builtin_fmaf(t, 1.061405429f, -1.453152027f),
                                 1.421413741f),
                          -0.284496736f),
                   0.254829592f);
  float e = __expf(-ax * ax);
  float erfax = __builtin_fmaf(-poly, e, 1.f);
  float er = copysignf(erfax, x);
  return 0.5f * v * (1.f + er);
}

// ---------------- merged weight abs-sum (3 tensors, 1 launch) ----------------
__global__ __launch_bounds__(256) void absum3_kernel(const float* __restrict__ Wg,
                                                     const float* __restrict__ W1,
                                                     const float* __restrict__ W2,
                                                     float* __restrict__ out) {
  int blk = blockIdx.x;
  const float* w; long n4; float* o; long lb; long nb;
  if (blk < 512)      { w = Wg; n4 = 3932160; o = &out[0]; lb = blk;       nb = 512; }
  else if (blk < 768) { w = W1; n4 = 1048576; o = &out[1]; lb = blk - 512; nb = 256; }
  else                { w = W2; n4 = 1048576; o = &out[2]; lb = blk - 768; nb = 256; }
  const float4* w4 = (const float4*)w;
  float s = 0.f;
  for (long i = lb * 256 + threadIdx.x; i < n4; i += nb * 256) {
    float4 v = w4[i];
    s += fabsf(v.x) + fabsf(v.y) + fabsf(v.z) + fabsf(v.w);
  }
  for (int off = 32; off; off >>= 1) s += __shfl_down(s, off);
  __shared__ float sb[4];
  int lane = threadIdx.x & 63, wid = threadIdx.x >> 6;
  if (lane == 0) sb[wid] = s;
  __syncthreads();
  if (threadIdx.x == 0) atomicAdd(o, sb[0] + sb[1] + sb[2] + sb[3]);
}

// ---------------- merged ternarize (3 tensors, 1 launch) ----------------
__global__ __launch_bounds__(256) void ternarize3_kernel(const float* __restrict__ Wg,
                                                         const float* __restrict__ W1,
                                                         const float* __restrict__ W2,
                                                         signed char* __restrict__ tg,
                                                         signed char* __restrict__ t1,
                                                         signed char* __restrict__ t2,
                                                         const float* __restrict__ sums) {
  int blk = blockIdx.x;
  const float* w; signed char* t; long n4; float ws; long lb; long nb;
  if (blk < 1024) {
    w = Wg; t = tg; n4 = 3932160; ws = sums[0] * (1.f / 15728640.f) + EPS; lb = blk; nb = 1024;
  } else if (blk < 1536) {
    w = W1; t = t1; n4 = 1048576; ws = sums[1] * (1.f / 4194304.f) + EPS; lb = blk - 1024; nb = 512;
  } else {
    w = W2; t = t2; n4 = 1048576; ws = sums[2] * (1.f / 4194304.f) + EPS; lb = blk - 1536; nb = 512;
  }
  // r6: one reciprocal per thread instead of 23.5M full-precision divides
  // (ws is uniform per tensor; rintf tie-flips are +-1 ternary unit, negligible)
  float rws = 1.f / ws;
  const float4* w4 = (const float4*)w;
  char4* t4 = (char4*)t;
  for (long i = lb * 256 + threadIdx.x; i < n4; i += nb * 256) {
    float4 v = w4[i];
    char4 c;
    c.x = (signed char)(int)fminf(fmaxf(rintf(v.x * rws), -1.f), 1.f);
    c.y = (signed char)(int)fminf(fmaxf(rintf(v.y * rws), -1.f), 1.f);
    c.z = (signed char)(int)fminf(fmaxf(rintf(v.z * rws), -1.f), 1.f);
    c.w = (signed char)(int)fminf(fmaxf(rintf(v.w * rws), -1.f), 1.f);
    t4[i] = c;
  }
}

// ---------------- LN1: write xn fp32 + per-row absmax ----------------
__global__ __launch_bounds__(256) void ln_rowmax_kernel(const float* __restrict__ x,
                                                        const float* __restrict__ w,
                                                        const float* __restrict__ b,
                                                        float* __restrict__ xn,
                                                        float* __restrict__ rowmax) {
  int m = blockIdx.x;
  int tid = threadIdx.x, lane = tid & 63, wid = tid >> 6;
  __shared__ float sb[4];
  float4 v = ((const float4*)(x + (long)m * 1024))[tid];
  float s = v.x + v.y + v.z + v.w;
  for (int off = 32; off; off >>= 1) s += __shfl_down(s, off);
  if (lane == 0) sb[wid] = s;
  __syncthreads();
  float mean = (sb[0] + sb[1] + sb[2] + sb[3]) * (1.f / 1024.f);
  __syncthreads();
  float dx = v.x - mean, dy = v.y - mean, dz = v.z - mean, dw = v.w - mean;
  float ss = dx * dx + dy * dy + dz * dz + dw * dw;
  for (int off = 32; off; off >>= 1) ss += __shfl_down(ss, off);
  if (lane == 0) sb[wid] = ss;
  __syncthreads();
  float rstd = rsqrtf((sb[0] + sb[1] + sb[2] + sb[3]) * (1.f / 1024.f) + EPS);
  __syncthreads();
  float4 wv = ((const float4*)w)[tid];
  float4 bv = ((const float4*)b)[tid];
  float4 o;
  o.x = dx * rstd * wv.x + bv.x;
  o.y = dy * rstd * wv.y + bv.y;
  o.z = dz * rstd * wv.z + bv.z;
  o.w = dw * rstd * wv.w + bv.w;
  ((float4*)(xn + (long)m * 1024))[tid] = o;
  float mx = fmaxf(fmaxf(fabsf(o.x), fabsf(o.y)), fmaxf(fabsf(o.z), fabsf(o.w)));
  for (int off = 32; off; off >>= 1) mx = fmaxf(mx, __shfl_down(mx, off));
  if (lane == 0) sb[wid] = mx;
  __syncthreads();
  if (tid == 0) rowmax[m] = fmaxf(fmaxf(sb[0], sb[1]), fmaxf(sb[2], sb[3]));
}

// ---------------- quantA: per-dest-row combined scale + gather-quantize ----------------
__global__ __launch_bounds__(256) void quantA_kernel(const float* __restrict__ xn,
                                                     const int* __restrict__ is0,
                                                     const int* __restrict__ is1,
                                                     const int* __restrict__ iv,
                                                     const float* __restrict__ rowmax,
                                                     const float* __restrict__ sums,
                                                     signed char* __restrict__ Aq,
                                                     float* __restrict__ s1) {
  int m = blockIdx.x;
  int b = m >> 8, l = m & 255;
  const float* rm = rowmax + b * 256;
  int src[15];
  src[0] = l;
#pragma unroll
  for (int j = 0; j < 3; ++j) { src[1 + j] = is0[l * 3 + j]; src[4 + j] = is1[l * 3 + j]; }
#pragma unroll
  for (int j = 0; j < 8; ++j) src[7 + j] = iv[l * 8 + j];
  float c = EPS;
#pragma unroll
  for (int sl = 0; sl < 15; ++sl) c = fmaxf(c, rm[src[sl]]);
  float xs = 127.f / c;
  if (threadIdx.x == 0) s1[m] = (sums[0] * (1.f / 15728640.f) + EPS) * c * (1.f / 127.f);
#pragma unroll
  for (int sl = 0; sl < 15; ++sl) {
    float4 v = ((const float4*)(xn + ((long)(b << 8) + src[sl]) * 1024))[threadIdx.x];
    char4 cc;
    cc.x = q8(v.x, xs); cc.y = q8(v.y, xs); cc.z = q8(v.z, xs); cc.w = q8(v.w, xs);
    *(char4*)&Aq[(long)m * 15360 + sl * 1024 + threadIdx.x * 4] = cc;
  }
}

// ---------------- fused: xag = x + s1*(acc0+acc1); LN2; quantize to int8 ----------------
__global__ __launch_bounds__(256) void ln_quant_acc_kernel(const int* __restrict__ accA,
                                                           const int* accB,
                                                           const float* __restrict__ x,
                                                           const float* __restrict__ s1,
                                                           const float* __restrict__ w,
                                                           const float* __restrict__ bb,
                                                           float* xag,
                                                           signed char* __restrict__ q,
                                                           float* __restrict__ srow,
                                                           const float* __restrict__ sum_ptr,
                                                           float inv_n) {
  int m = blockIdx.x;
  int tid = threadIdx.x, lane = tid & 63, wid = tid >> 6;
  __shared__ float sb[4];
  float sm = s1[m];
  int4 a0 = ((const int4*)(accA + (long)m * 1024))[tid];
  int4 a1 = ((const int4*)(accB + (long)m * 1024))[tid];
  float4 xv = ((const float4*)(x + (long)m * 1024))[tid];
  float4 v;
  v.x = xv.x + sm * (float)(a0.x + a1.x);
  v.y = xv.y + sm * (float)(a0.y + a1.y);
  v.z = xv.z + sm * (float)(a0.z + a1.z);
  v.w = xv.w + sm * (float)(a0.w + a1.w);
  ((float4*)(xag + (long)m * 1024))[tid] = v;
  float s = v.x + v.y + v.z + v.w;
  for (int off = 32; off; off >>= 1) s += __shfl_down(s, off);
  if (lane == 0) sb[wid] = s;
  __syncthreads();
  float mean = (sb[0] + sb[1] + sb[2] + sb[3]) * (1.f / 1024.f);
  __syncthreads();
  float dx = v.x - mean, dy = v.y - mean, dz = v.z - mean, dw = v.w - mean;
  float ss = dx * dx + dy * dy + dz * dz + dw * dw;
  for (int off = 32; off; off >>= 1) ss += __shfl_down(ss, off);
  if (lane == 0) sb[wid] = ss;
  __syncthreads();
  float rstd = rsqrtf((sb[0] + sb[1] + sb[2] + sb[3]) * (1.f / 1024.f) + EPS);
  __syncthreads();
  float4 wv = ((const float4*)w)[tid];
  float4 bv = ((const float4*)bb)[tid];
  float nx = dx * rstd * wv.x + bv.x;
  float ny = dy * rstd * wv.y + bv.y;
  float nz = dz * rstd * wv.z + bv.z;
  float nw = dw * rstd * wv.w + bv.w;
  float mx = fmaxf(fmaxf(fabsf(nx), fabsf(ny)), fmaxf(fabsf(nz), fabsf(nw)));
  for (int off = 32; off; off >>= 1) mx = fmaxf(mx, __shfl_down(mx, off));
  if (lane == 0) sb[wid] = mx;
  __syncthreads();
  float rmax = fmaxf(fmaxf(fmaxf(sb[0], sb[1]), fmaxf(sb[2], sb[3])), EPS);
  float xs = 127.f / rmax;
  char4 c;
  c.x = q8(nx, xs); c.y = q8(ny, xs); c.z = q8(nz, xs); c.w = q8(nw, xs);
  *(char4*)&q[(long)m * 1024 + tid * 4] = c;
  if (tid == 0) srow[m] = (sum_ptr[0] * inv_n + EPS) * rmax * (1.f / 127.f);
}

// ---------------- row quantize [8192,4096] bf16 -> int8 ----------------
__global__ __launch_bounds__(256) void rowquant4k_kernel(const unsigned short* __restrict__ g,
                                                         signed char* __restrict__ q,
                                                         float* __restrict__ srow,
                                                         const float* __restrict__ sum_ptr,
                                                         float inv_n) {
  int m = blockIdx.x;
  int tid = threadIdx.x, lane = tid & 63, wid = tid >> 6;
  __shared__ float sb[4];
  const uint4* gr = (const uint4*)(g + (long)m * 4096);  // 16B = 8 bf16
  float f[16];
  float mx = 0.f;
#pragma unroll
  for (int i = 0; i < 2; ++i) {
    uint4 u = gr[tid + i * 256];
    unsigned uu[4] = {u.x, u.y, u.z, u.w};
#pragma unroll
    for (int j = 0; j < 4; ++j) {
      float lo = bf2f((unsigned short)(uu[j] & 0xFFFF));
      float hi = bf2f((unsigned short)(uu[j] >> 16));
      f[i * 8 + j * 2] = lo;
      f[i * 8 + j * 2 + 1] = hi;
      mx = fmaxf(mx, fmaxf(fabsf(lo), fabsf(hi)));
    }
  }
  for (int off = 32; off; off >>= 1) mx = fmaxf(mx, __shfl_down(mx, off));
  if (lane == 0) sb[wid] = mx;
  __syncthreads();
  float rmax = fmaxf(fmaxf(fmaxf(sb[0], sb[1]), fmaxf(sb[2], sb[3])), EPS);
  float xs = 127.f / rmax;
#pragma unroll
  for (int i = 0; i < 2; ++i) {
    char4 c0, c1;
    c0.x = q8(f[i * 8 + 0], xs); c0.y = q8(f[i * 8 + 1], xs);
    c0.z = q8(f[i * 8 + 2], xs); c0.w = q8(f[i * 8 + 3], xs);
    c1.x = q8(f[i * 8 + 4], xs); c1.y = q8(f[i * 8 + 5], xs);
    c1.z = q8(f[i * 8 + 6], xs); c1.w = q8(f[i * 8 + 7], xs);
    long base = (long)m * 4096 + (tid + i * 256) * 8;
    *(char4*)&q[base] = c0;
    *(char4*)&q[base + 4] = c1;
  }
  if (tid == 0) srow[m] = (sum_ptr[0] * inv_n + EPS) * rmax * (1.f / 127.f);
}

// ---------------- final residual: out = xag + s3*(acc0+acc1) ----------------
__global__ __launch_bounds__(256) void reduce3_kernel(const int* __restrict__ accA,
                                                      const int* __restrict__ accB,
                                                      const float* __restrict__ xag,
                                                      const float* __restrict__ s3,
                                                      float* __restrict__ out) {
  int m = blockIdx.x;
  float sm = s3[m];
  int4 a0 = ((const int4*)(accA + (long)m * 1024))[threadIdx.x];
  int4 a1 = ((const int4*)(accB + (long)m * 1024))[threadIdx.x];
  float4 xv = ((const float4*)(xag + (long)m * 1024))[threadIdx.x];
  float4 o;
  o.x = xv.x + sm * (float)(a0.x + a1.x);
  o.y = xv.y + sm * (float)(a0.y + a1.y);
  o.z = xv.z + sm * (float)(a0.z + a1.z);
  o.w = xv.w + sm * (float)(a0.w + a1.w);
  ((float4*)(out + (long)m * 1024))[threadIdx.x] = o;
}

// ============================================================================
// int8 GEMM, 256x256 tile, BK=128, 8 waves (2Mx4N), 16x16x64 MFMA.
// r6 = r5 schedule UNCHANGED (m201 8-phase rhythm, tail-drain-fixed; 136 us
// GEMM1, MfmaUtil 39%). r5 falsified the 8-phase hypothesis for i8 at this
// geometry (r2/r3/r5 all ~137 us = serial pipe-sum fixed point); GEMM work is
// frozen. r6 changes ONLY: mode-1 epilogue erff -> gelu_f poly (A&S 7.1.26).
// Schedule audit unchanged from r5 (see r5 comments).
// mode 1: outh[m,n] = bf16(gelu(scale[m]*acc));  mode 2: iacc store.
// ============================================================================

#define LGKM(n) do { asm volatile("s_waitcnt lgkmcnt(" #n ")" ::: "memory"); \
                     __builtin_amdgcn_sched_barrier(0); } while (0)
#define VMC(n)  do { asm volatile("s_waitcnt vmcnt(" #n ")" ::: "memory");   \
                     __builtin_amdgcn_sched_barrier(0); } while (0)
#define SBAR    __builtin_amdgcn_s_barrier()
#define SCHED0  __builtin_amdgcn_sched_barrier(0)

#define RD16(P, O) (*(const v4i*)((P) + (O)))

// read one A-half (8 ds_read_b128) / one B-half (4 ds_read_b128)
#define RDA(arr, BO, QMOFS)                                                    \
  do { _Pragma("unroll") for (int m2 = 0; m2 < 4; ++m2) {                      \
    arr[m2][0] = RD16(pA0, (BO) + (QMOFS) + m2 * 2048);                        \
    arr[m2][1] = RD16(pA1, (BO) + (QMOFS) + m2 * 2048);                        \
  } SCHED0; } while (0)
#define RDB(arr, BO, QNOFS)                                                    \
  do { _Pragma("unroll") for (int n2 = 0; n2 < 2; ++n2) {                      \
    arr[n2][0] = RD16(pB0, (BO) + (QNOFS) + n2 * 2048);                        \
    arr[n2][1] = RD16(pB1, (BO) + (QNOFS) + n2 * 2048);                        \
  } SCHED0; } while (0)

// one C-quadrant (QM,QN): 16 MFMA, all-static acc indexing
#define MFQ(Af, Bf, QM, QN)                                                    \
  do {                                                                         \
    __builtin_amdgcn_s_setprio(1);                                             \
    _Pragma("unroll") for (int m2 = 0; m2 < 4; ++m2) {                         \
      _Pragma("unroll") for (int n2 = 0; n2 < 2; ++n2) {                       \
        acc[(QM)*4 + m2][(QN)*2 + n2] = __builtin_amdgcn_mfma_i32_16x16x64_i8( \
            Af[m2][0], Bf[n2][0], acc[(QM)*4 + m2][(QN)*2 + n2], 0, 0, 0);     \
        acc[(QM)*4 + m2][(QN)*2 + n2] = __builtin_amdgcn_mfma_i32_16x16x64_i8( \
            Af[m2][1], Bf[n2][1], acc[(QM)*4 + m2][(QN)*2 + n2], 0, 0, 0);     \
      }                                                                        \
    }                                                                          \
    __builtin_amdgcn_s_setprio(0);                                             \
  } while (0)

__global__ __launch_bounds__(512, 2) void gemm_i8_p(const signed char* __restrict__ A,
                                                    const signed char* __restrict__ Bw,
                                                    __hip_bfloat16* __restrict__ outh,
                                                    int* __restrict__ iacc0,
                                                    int* __restrict__ iacc1,
                                                    const float* __restrict__ scale,
                                                    int N, long K, int nt, int mode,
                                                    int nM, int nN) {
  __shared__ __align__(16) signed char lds[131072];  // A: [0,64K), B: [64K,128K)
  const int tid = threadIdx.x;
  const int lane = tid & 63;
  const int wave = tid >> 6;
  const int wm = wave >> 2, wn = wave & 3;  // 2x4 wave grid, 128x64 C per wave
  const int r15 = lane & 15, quad = lane >> 4, sw = lane & 7;

  // mt fastest (no XCD swizzle: same-mt => same XCD => A-panel L2 reuse)
  const int g = (int)blockIdx.x;
  const int mt = g % nM;
  const int rest = g / nM;
  const int ntl = rest % nN;
  const int z = rest / nN;
  const long m0 = (long)mt * 256, n0 = (long)ntl * 256;
  const signed char* Ab = A + m0 * K;
  const signed char* Bb = Bw + n0 * K;
  const long k0base = (long)z * nt * 128;

  // glds per-lane 32-bit global offsets (4 chunks; identical for A and B)
  unsigned voff[4];
#pragma unroll
  for (int i = 0; i < 4; ++i) {
    int c = wave * 64 + i * 512 + lane;
    int row = c >> 3;
    int blk = (c & 7) ^ (row & 7);  // pre-swizzled source column block
    voff[i] = (unsigned)row * (unsigned)K + (unsigned)(blk << 4);
  }

  // ds_read base pointers (k-slice 0/1 have different XOR'd column offsets)
  const signed char* pA0 = lds + (wm * 128 + r15) * 128 + ((quad ^ sw) << 4);
  const signed char* pA1 = lds + (wm * 128 + r15) * 128 + (((quad + 4) ^ sw) << 4);
  const signed char* pB0 = lds + 65536 + (wn * 64 + r15) * 128 + ((quad ^ sw) << 4);
  const signed char* pB1 = lds + 65536 + (wn * 64 + r15) * 128 + (((quad + 4) ^ sw) << 4);

  v4i a0[4][2], a1[4][2], b0[2][2], b1[2][2];
  v4i acc[8][4] = {};

  // stage pair i: one A-chunk + one B-chunk (2 glds, 2 KiB total per wave)
#define STAGE_PAIR(BO, KOFF, i)                                                \
  do {                                                                         \
    int cb = wave * 64 + (i) * 512;                                            \
    glds16(Ab + (KOFF) + voff[i], (void*)(lds + (BO) + cb * 16));              \
    glds16(Bb + (KOFF) + voff[i], (void*)(lds + 65536 + (BO) + cb * 16));      \
  } while (0)

  // ---- prologue: tile0 fully (8), tile1 partial (6); wait tile0; SBAR ----
  STAGE_PAIR(0, k0base, 0);
  STAGE_PAIR(0, k0base, 1);
  STAGE_PAIR(0, k0base, 2);
  STAGE_PAIR(0, k0base, 3);
  if (nt > 1) {
    STAGE_PAIR(32768, k0base + 128, 0);
    STAGE_PAIR(32768, k0base + 128, 1);
    STAGE_PAIR(32768, k0base + 128, 2);
    VMC(6);  // drains tile0's 8 (leaves tile1's 6)
  } else {
    VMC(0);
  }
  SBAR;

  for (int t = 0; t < nt; ++t) {
    const int bo = (t & 1) << 15;
    const int bn = bo ^ 32768;
    // ---- ph0: tail-stage t+1; reads a0,b0; SBAR; lgkm(0); MFQ00; SBAR ----
    if (t + 1 < nt) { STAGE_PAIR(bn, k0base + (long)(t + 1) * 128, 3); }
    RDA(a0, bo, 0);
    RDB(b0, bo, 0);
    SBAR;
    LGKM(0);
    MFQ(a0, b0, 0, 0);
    SBAR;
    // ---- ph1: reads b1; SBAR; lgkm(0); MFQ01; SBAR ----
    RDB(b1, bo, 4096);
    SBAR;
    LGKM(0);
    MFQ(a0, b1, 0, 1);
    SBAR;
    // ---- ph2: reads a1; SBAR; lgkm(0); MFQ10; SBAR ----
    RDA(a1, bo, 8192);
    SBAR;
    LGKM(0);
    MFQ(a1, b0, 1, 0);
    SBAR;  // after this: all waves' buf-p reads retired -> p overwrite-safe
    // ---- ph3 (read-free): stage 6 for t+2 into p; MFQ11; counted wait ----
    if (t + 2 < nt) {
      long kN2 = k0base + (long)(t + 2) * 128;
      STAGE_PAIR(bo, kN2, 0);
      STAGE_PAIR(bo, kN2, 1);
      STAGE_PAIR(bo, kN2, 2);
    }
    SBAR;
    MFQ(a1, b1, 1, 1);
    // VMC(6) only valid when ph3 just issued 6 new glds (queue = t+1's 8 +
    // t+2's 6). At t==nt-2 nothing was staged -> drain fully (r4 race fix).
    if (t + 2 < nt) { VMC(6); }
    else           { VMC(0); }
    SBAR;
  }

  // ---- epilogue: C layout col=lane&15, row=quad*4+reg (harness-verified) ----
  if (mode == 2) {
    int* iacc = z ? iacc1 : iacc0;
#pragma unroll
    for (int mi = 0; mi < 8; ++mi) {
#pragma unroll
      for (int r = 0; r < 4; ++r) {
        long m = m0 + wm * 128 + mi * 16 + quad * 4 + r;
        int* arow = iacc + m * N;
#pragma unroll
        for (int ni = 0; ni < 4; ++ni)
          arow[n0 + wn * 64 + ni * 16 + r15] = acc[mi][ni][r];
      }
    }
  } else {
#pragma unroll
    for (int mi = 0; mi < 8; ++mi) {
#pragma unroll
      for (int r = 0; r < 4; ++r) {
        long m = m0 + wm * 128 + mi * 16 + quad * 4 + r;
        float sm = scale[m];
        __hip_bfloat16* orow = outh + m * N;
#pragma unroll
        for (int ni = 0; ni < 4; ++ni) {
          float v = sm * (float)acc[mi][ni][r];
          orow[n0 + wn * 64 + ni * 16 + r15] = __float2bfloat16(gelu_f(v));
        }
      }
    }
  }
}

extern "C" void kernel_launch(void* const* d_in, const int* in_sizes, int n_in,
                              void* d_out, int out_size, void* d_ws, size_t ws_size,
                              hipStream_t stream) {
  const float* x    = (const float*)d_in[0];
  const float* ln1w = (const float*)d_in[1];
  const float* ln1b = (const float*)d_in[2];
  const float* ln2w = (const float*)d_in[3];
  const float* ln2b = (const float*)d_in[4];
  const float* Wg   = (const float*)d_in[5];
  const float* W1   = (const float*)d_in[6];
  const float* W2   = (const float*)d_in[7];
  const int* is0    = (const int*)d_in[8];
  const int* is1    = (const int*)d_in[9];
  const int* iv     = (const int*)d_in[10];
  float* out = (float*)d_out;

  // workspace layout, peak ~234 MB (unchanged from verified layout):
  char* ws = (char*)d_ws;
  float* sums = (float*)ws;                                   // 3 floats (+pad)
  signed char* t_g = (signed char*)(ws + 256);                // 15,728,640
  signed char* t_1 = t_g + 15728640;                          //  4,194,304
  signed char* t_2 = t_1 + 4194304;                           //  4,194,304
  float* rowmax1 = (float*)(t_2 + 4194304);                   // 32 KB
  float* s1  = rowmax1 + 8192;
  float* s2  = s1 + 8192;
  float* s3  = s2 + 8192;
  float* xag = s3 + 8192;
  int* acc1b = (int*)xag;
  signed char* hq = (signed char*)(xag + 8388608);            //  8.39 MB
  float* xn = (float*)(hq + 8388608);
  int* acc1a = (int*)xn;
  signed char* q3 = (signed char*)xn;
  signed char* Aq = (signed char*)(xn + 8388608);
  unsigned short* gg = (unsigned short*)Aq;
  int* acc3a = (int*)Aq;
  int* acc3b = acc3a + 8192l * 1024;

  hipMemsetAsync(sums, 0, 64, stream);
  absum3_kernel<<<1024, 256, 0, stream>>>(Wg, W1, W2, sums);
  ternarize3_kernel<<<2048, 256, 0, stream>>>(Wg, W1, W2, t_g, t_1, t_2, sums);
  ln_rowmax_kernel<<<8192, 256, 0, stream>>>(x, ln1w, ln1b, xn, rowmax1);
  quantA_kernel<<<8192, 256, 0, stream>>>(xn, is0, is1, iv, rowmax1, sums, Aq, s1);
  // GEMM1: M=8192 N=1024 K=15360, split-K=2 -> 32*4*2 = 256 blocks (1/CU)
  gemm_i8_p<<<256, 512, 0, stream>>>(Aq, t_g, nullptr, acc1a, acc1b, nullptr,
                                     1024, 15360L, 60, 2, 32, 4);
  ln_quant_acc_kernel<<<8192, 256, 0, stream>>>(acc1a, acc1b, x, s1, ln2w, ln2b, xag, hq, s2,
                                                &sums[1], 1.f / 4194304.f);
  // GEMM2: M=8192 N=4096 K=1024, gelu -> bf16, 32*16 = 512 blocks
  gemm_i8_p<<<512, 512, 0, stream>>>(hq, t_1, (__hip_bfloat16*)gg, nullptr, nullptr,
                                     s2, 4096, 1024L, 8, 1, 32, 16);
  rowquant4k_kernel<<<8192, 256, 0, stream>>>(gg, q3, s3, &sums[2], 1.f / 4194304.f);
  // GEMM3: M=8192 N=1024 K=4096, split-K=2 -> 256 blocks
  gemm_i8_p<<<256, 512, 0, stream>>>(q3, t_2, nullptr, acc3a, acc3b, nullptr,
                                     1024, 4096L, 16, 2, 32, 4);
  reduce3_kernel<<<8192, 256, 0, stream>>>(acc3a, acc3b, xag, s3, out);
}

// Round 7
// 515.630 us; speedup vs baseline: 1.0512x; 1.0111x over previous
//
#include <hip/hip_runtime.h>
#include <hip/hip_bf16.h>
#include <math.h>
#include <stdint.h>

#define EPS 1e-5f

typedef int v4i __attribute__((ext_vector_type(4)));

__device__ __forceinline__ void glds16(const void* g, void* l) {
  __builtin_amdgcn_global_load_lds(
      (const __attribute__((address_space(1))) void*)g,
      (__attribute__((address_space(3))) void*)l, 16, 0, 0);
}

__device__ __forceinline__ signed char q8(float f, float xs) {
  float r = rintf(f * xs);
  r = fminf(fmaxf(r, -128.f), 127.f);
  return (signed char)(int)r;
}

// pack 4 quantized values into one dword (keeps everything in registers)
__device__ __forceinline__ unsigned packq4(float4 v, float xs) {
  unsigned r0 = (unsigned)(unsigned char)q8(v.x, xs);
  unsigned r1 = (unsigned)(unsigned char)q8(v.y, xs);
  unsigned r2 = (unsigned)(unsigned char)q8(v.z, xs);
  unsigned r3 = (unsigned)(unsigned char)q8(v.w, xs);
  return r0 | (r1 << 8) | (r2 << 16) | (r3 << 24);
}

__device__ __forceinline__ float bf2f(unsigned short h) {
  return __builtin_bit_cast(float, (unsigned)h << 16);
}

// r7: sigmoid-form gelu: v*sigmoid(1.702v). ~5 VALU inst (vs 15 for A&S poly,
// ~30+ for libm erff). Max |err| vs exact gelu ~0.02 ~= 1 int8 LSB downstream
// (output immediately row-quantized, step ~rowmax/127); absmax headroom 3x.
__device__ __forceinline__ float gelu_f(float v) {
  float e = __expf(-1.702f * v);
  return v * __builtin_amdgcn_rcpf(1.f + e);
}

// ============ prep1: absum3 (blocks 0..1023) + LN1/rowmax (1024..9215) ======
__global__ __launch_bounds__(256) void prep1_kernel(const float* __restrict__ Wg,
                                                    const float* __restrict__ W1,
                                                    const float* __restrict__ W2,
                                                    float* __restrict__ sums,
                                                    const float* __restrict__ x,
                                                    const float* __restrict__ lw,
                                                    const float* __restrict__ lb,
                                                    float* __restrict__ xn,
                                                    float* __restrict__ rowmax) {
  int blk = blockIdx.x;
  int tid = threadIdx.x, lane = tid & 63, wid = tid >> 6;
  __shared__ float sb[4];
  if (blk < 1024) {
    // ---- absum3 part ----
    const float* w; long n4; float* o; long lb2; long nb;
    if (blk < 512)      { w = Wg; n4 = 3932160; o = &sums[0]; lb2 = blk;       nb = 512; }
    else if (blk < 768) { w = W1; n4 = 1048576; o = &sums[1]; lb2 = blk - 512; nb = 256; }
    else                { w = W2; n4 = 1048576; o = &sums[2]; lb2 = blk - 768; nb = 256; }
    const float4* w4 = (const float4*)w;
    float s = 0.f;
    for (long i = lb2 * 256 + tid; i < n4; i += nb * 256) {
      float4 v = w4[i];
      s += fabsf(v.x) + fabsf(v.y) + fabsf(v.z) + fabsf(v.w);
    }
    for (int off = 32; off; off >>= 1) s += __shfl_down(s, off);
    if (lane == 0) sb[wid] = s;
    __syncthreads();
    if (tid == 0) atomicAdd(o, sb[0] + sb[1] + sb[2] + sb[3]);
    return;
  }
  // ---- LN1 + rowmax part ----
  int m = blk - 1024;
  float4 v = ((const float4*)(x + (long)m * 1024))[tid];
  float s = v.x + v.y + v.z + v.w;
  for (int off = 32; off; off >>= 1) s += __shfl_down(s, off);
  if (lane == 0) sb[wid] = s;
  __syncthreads();
  float mean = (sb[0] + sb[1] + sb[2] + sb[3]) * (1.f / 1024.f);
  __syncthreads();
  float dx = v.x - mean, dy = v.y - mean, dz = v.z - mean, dw = v.w - mean;
  float ss = dx * dx + dy * dy + dz * dz + dw * dw;
  for (int off = 32; off; off >>= 1) ss += __shfl_down(ss, off);
  if (lane == 0) sb[wid] = ss;
  __syncthreads();
  float rstd = rsqrtf((sb[0] + sb[1] + sb[2] + sb[3]) * (1.f / 1024.f) + EPS);
  __syncthreads();
  float4 wv = ((const float4*)lw)[tid];
  float4 bv = ((const float4*)lb)[tid];
  float4 o;
  o.x = dx * rstd * wv.x + bv.x;
  o.y = dy * rstd * wv.y + bv.y;
  o.z = dz * rstd * wv.z + bv.z;
  o.w = dw * rstd * wv.w + bv.w;
  ((float4*)(xn + (long)m * 1024))[tid] = o;
  float mx = fmaxf(fmaxf(fabsf(o.x), fabsf(o.y)), fmaxf(fabsf(o.z), fabsf(o.w)));
  for (int off = 32; off; off >>= 1) mx = fmaxf(mx, __shfl_down(mx, off));
  if (lane == 0) sb[wid] = mx;
  __syncthreads();
  if (tid == 0) rowmax[m] = fmaxf(fmaxf(sb[0], sb[1]), fmaxf(sb[2], sb[3]));
}

// ==== prep2: ternarize3 (blocks 0..2047) + quantA vec16 (2048..10239) =======
__global__ __launch_bounds__(256) void prep2_kernel(const float* __restrict__ Wg,
                                                    const float* __restrict__ W1,
                                                    const float* __restrict__ W2,
                                                    signed char* __restrict__ tg,
                                                    signed char* __restrict__ t1,
                                                    signed char* __restrict__ t2,
                                                    const float* __restrict__ sums,
                                                    const float* __restrict__ xn,
                                                    const int* __restrict__ is0,
                                                    const int* __restrict__ is1,
                                                    const int* __restrict__ iv,
                                                    const float* __restrict__ rowmax,
                                                    signed char* __restrict__ Aq,
                                                    float* __restrict__ s1) {
  int blk = blockIdx.x;
  if (blk < 2048) {
    // ---- ternarize part (one rcp/thread instead of 23.5M divides) ----
    const float* w; signed char* t; long n4; float ws; long lb; long nb;
    if (blk < 1024) {
      w = Wg; t = tg; n4 = 3932160; ws = sums[0] * (1.f / 15728640.f) + EPS; lb = blk; nb = 1024;
    } else if (blk < 1536) {
      w = W1; t = t1; n4 = 1048576; ws = sums[1] * (1.f / 4194304.f) + EPS; lb = blk - 1024; nb = 512;
    } else {
      w = W2; t = t2; n4 = 1048576; ws = sums[2] * (1.f / 4194304.f) + EPS; lb = blk - 1536; nb = 512;
    }
    float rws = 1.f / ws;
    const float4* w4 = (const float4*)w;
    char4* t4 = (char4*)t;
    for (long i = lb * 256 + threadIdx.x; i < n4; i += nb * 256) {
      float4 v = w4[i];
      char4 c;
      c.x = (signed char)(int)fminf(fmaxf(rintf(v.x * rws), -1.f), 1.f);
      c.y = (signed char)(int)fminf(fmaxf(rintf(v.y * rws), -1.f), 1.f);
      c.z = (signed char)(int)fminf(fmaxf(rintf(v.z * rws), -1.f), 1.f);
      c.w = (signed char)(int)fminf(fmaxf(rintf(v.w * rws), -1.f), 1.f);
      t4[i] = c;
    }
    return;
  }
  // ---- quantA part: per-dest-row scale + gather-quantize, 16 B/lane writes.
  // Wave w handles slices {w, w+4, w+8, w+12} (wave 3: 3 slices); each lane
  // quantizes 16 consecutive elements: 4x float4 read (64 B/lane, coalesced),
  // one uint4 write (16 B/lane, coalesced) -- vs r6's 15 char4 stores.
  int m = blk - 2048;
  int b = m >> 8, l = m & 255;
  const float* rm = rowmax + b * 256;
  int src[15];
  src[0] = l;
#pragma unroll
  for (int j = 0; j < 3; ++j) { src[1 + j] = is0[l * 3 + j]; src[4 + j] = is1[l * 3 + j]; }
#pragma unroll
  for (int j = 0; j < 8; ++j) src[7 + j] = iv[l * 8 + j];
  float c = EPS;
#pragma unroll
  for (int sl = 0; sl < 15; ++sl) c = fmaxf(c, rm[src[sl]]);
  float xs = 127.f / c;
  if (threadIdx.x == 0) s1[m] = (sums[0] * (1.f / 15728640.f) + EPS) * c * (1.f / 127.f);
  const int col = (threadIdx.x & 63) * 16;  // element offset in the 1024-col row
  const int sg = threadIdx.x >> 6;          // wave id = slice group
  for (int sl = sg; sl < 15; sl += 4) {
    const float4* p = (const float4*)(xn + ((long)(b << 8) + src[sl]) * 1024 + col);
    float4 v0 = p[0], v1 = p[1], v2 = p[2], v3 = p[3];
    uint4 o;
    o.x = packq4(v0, xs);
    o.y = packq4(v1, xs);
    o.z = packq4(v2, xs);
    o.w = packq4(v3, xs);
    *(uint4*)&Aq[(long)m * 15360 + sl * 1024 + col] = o;
  }
}

// ---------------- fused: xag = x + s1*(acc0+acc1); LN2; quantize to int8 ----------------
__global__ __launch_bounds__(256) void ln_quant_acc_kernel(const int* __restrict__ accA,
                                                           const int* accB,
                                                           const float* __restrict__ x,
                                                           const float* __restrict__ s1,
                                                           const float* __restrict__ w,
                                                           const float* __restrict__ bb,
                                                           float* xag,
                                                           signed char* __restrict__ q,
                                                           float* __restrict__ srow,
                                                           const float* __restrict__ sum_ptr,
                                                           float inv_n) {
  int m = blockIdx.x;
  int tid = threadIdx.x, lane = tid & 63, wid = tid >> 6;
  __shared__ float sb[4];
  float sm = s1[m];
  int4 a0 = ((const int4*)(accA + (long)m * 1024))[tid];
  int4 a1 = ((const int4*)(accB + (long)m * 1024))[tid];
  float4 xv = ((const float4*)(x + (long)m * 1024))[tid];
  float4 v;
  v.x = xv.x + sm * (float)(a0.x + a1.x);
  v.y = xv.y + sm * (float)(a0.y + a1.y);
  v.z = xv.z + sm * (float)(a0.z + a1.z);
  v.w = xv.w + sm * (float)(a0.w + a1.w);
  ((float4*)(xag + (long)m * 1024))[tid] = v;
  float s = v.x + v.y + v.z + v.w;
  for (int off = 32; off; off >>= 1) s += __shfl_down(s, off);
  if (lane == 0) sb[wid] = s;
  __syncthreads();
  float mean = (sb[0] + sb[1] + sb[2] + sb[3]) * (1.f / 1024.f);
  __syncthreads();
  float dx = v.x - mean, dy = v.y - mean, dz = v.z - mean, dw = v.w - mean;
  float ss = dx * dx + dy * dy + dz * dz + dw * dw;
  for (int off = 32; off; off >>= 1) ss += __shfl_down(ss, off);
  if (lane == 0) sb[wid] = ss;
  __syncthreads();
  float rstd = rsqrtf((sb[0] + sb[1] + sb[2] + sb[3]) * (1.f / 1024.f) + EPS);
  __syncthreads();
  float4 wv = ((const float4*)w)[tid];
  float4 bv = ((const float4*)bb)[tid];
  float nx = dx * rstd * wv.x + bv.x;
  float ny = dy * rstd * wv.y + bv.y;
  float nz = dz * rstd * wv.z + bv.z;
  float nw = dw * rstd * wv.w + bv.w;
  float mx = fmaxf(fmaxf(fabsf(nx), fabsf(ny)), fmaxf(fabsf(nz), fabsf(nw)));
  for (int off = 32; off; off >>= 1) mx = fmaxf(mx, __shfl_down(mx, off));
  if (lane == 0) sb[wid] = mx;
  __syncthreads();
  float rmax = fmaxf(fmaxf(fmaxf(sb[0], sb[1]), fmaxf(sb[2], sb[3])), EPS);
  float xs = 127.f / rmax;
  char4 c;
  c.x = q8(nx, xs); c.y = q8(ny, xs); c.z = q8(nz, xs); c.w = q8(nw, xs);
  *(char4*)&q[(long)m * 1024 + tid * 4] = c;
  if (tid == 0) srow[m] = (sum_ptr[0] * inv_n + EPS) * rmax * (1.f / 127.f);
}

// ---------------- row quantize [8192,4096] bf16 -> int8 ----------------
__global__ __launch_bounds__(256) void rowquant4k_kernel(const unsigned short* __restrict__ g,
                                                         signed char* __restrict__ q,
                                                         float* __restrict__ srow,
                                                         const float* __restrict__ sum_ptr,
                                                         float inv_n) {
  int m = blockIdx.x;
  int tid = threadIdx.x, lane = tid & 63, wid = tid >> 6;
  __shared__ float sb[4];
  const uint4* gr = (const uint4*)(g + (long)m * 4096);  // 16B = 8 bf16
  float f[16];
  float mx = 0.f;
#pragma unroll
  for (int i = 0; i < 2; ++i) {
    uint4 u = gr[tid + i * 256];
    unsigned uu[4] = {u.x, u.y, u.z, u.w};
#pragma unroll
    for (int j = 0; j < 4; ++j) {
      float lo = bf2f((unsigned short)(uu[j] & 0xFFFF));
      float hi = bf2f((unsigned short)(uu[j] >> 16));
      f[i * 8 + j * 2] = lo;
      f[i * 8 + j * 2 + 1] = hi;
      mx = fmaxf(mx, fmaxf(fabsf(lo), fabsf(hi)));
    }
  }
  for (int off = 32; off; off >>= 1) mx = fmaxf(mx, __shfl_down(mx, off));
  if (lane == 0) sb[wid] = mx;
  __syncthreads();
  float rmax = fmaxf(fmaxf(fmaxf(sb[0], sb[1]), fmaxf(sb[2], sb[3])), EPS);
  float xs = 127.f / rmax;
#pragma unroll
  for (int i = 0; i < 2; ++i) {
    char4 c0, c1;
    c0.x = q8(f[i * 8 + 0], xs); c0.y = q8(f[i * 8 + 1], xs);
    c0.z = q8(f[i * 8 + 2], xs); c0.w = q8(f[i * 8 + 3], xs);
    c1.x = q8(f[i * 8 + 4], xs); c1.y = q8(f[i * 8 + 5], xs);
    c1.z = q8(f[i * 8 + 6], xs); c1.w = q8(f[i * 8 + 7], xs);
    long base = (long)m * 4096 + (tid + i * 256) * 8;
    *(char4*)&q[base] = c0;
    *(char4*)&q[base + 4] = c1;
  }
  if (tid == 0) srow[m] = (sum_ptr[0] * inv_n + EPS) * rmax * (1.f / 127.f);
}

// ---------------- final residual: out = xag + s3*(acc0+acc1) ----------------
__global__ __launch_bounds__(256) void reduce3_kernel(const int* __restrict__ accA,
                                                      const int* __restrict__ accB,
                                                      const float* __restrict__ xag,
                                                      const float* __restrict__ s3,
                                                      float* __restrict__ out) {
  int m = blockIdx.x;
  float sm = s3[m];
  int4 a0 = ((const int4*)(accA + (long)m * 1024))[threadIdx.x];
  int4 a1 = ((const int4*)(accB + (long)m * 1024))[threadIdx.x];
  float4 xv = ((const float4*)(xag + (long)m * 1024))[threadIdx.x];
  float4 o;
  o.x = xv.x + sm * (float)(a0.x + a1.x);
  o.y = xv.y + sm * (float)(a0.y + a1.y);
  o.z = xv.z + sm * (float)(a0.z + a1.z);
  o.w = xv.w + sm * (float)(a0.w + a1.w);
  ((float4*)(out + (long)m * 1024))[threadIdx.x] = o;
}

// ============================================================================
// int8 GEMM, 256x256 tile, BK=128, 8 waves (2Mx4N), 16x16x64 MFMA.
// r7 = r5/r6 schedule UNCHANGED (m201 8-phase rhythm, tail-drain-fixed;
// 135 us GEMM1, MfmaUtil 40% -- the i8 serial pipe-sum fixed point; GEMM
// scheduling work is frozen after r2/r3/r5 falsification). r7 changes ONLY
// the mode-1 epilogue gelu (poly -> sigmoid form, 5 inst).
// Schedule audit: see r5 comments.
// mode 1: outh[m,n] = bf16(gelu(scale[m]*acc));  mode 2: iacc store.
// ============================================================================

#define LGKM(n) do { asm volatile("s_waitcnt lgkmcnt(" #n ")" ::: "memory"); \
                     __builtin_amdgcn_sched_barrier(0); } while (0)
#define VMC(n)  do { asm volatile("s_waitcnt vmcnt(" #n ")" ::: "memory");   \
                     __builtin_amdgcn_sched_barrier(0); } while (0)
#define SBAR    __builtin_amdgcn_s_barrier()
#define SCHED0  __builtin_amdgcn_sched_barrier(0)

#define RD16(P, O) (*(const v4i*)((P) + (O)))

// read one A-half (8 ds_read_b128) / one B-half (4 ds_read_b128)
#define RDA(arr, BO, QMOFS)                                                    \
  do { _Pragma("unroll") for (int m2 = 0; m2 < 4; ++m2) {                      \
    arr[m2][0] = RD16(pA0, (BO) + (QMOFS) + m2 * 2048);                        \
    arr[m2][1] = RD16(pA1, (BO) + (QMOFS) + m2 * 2048);                        \
  } SCHED0; } while (0)
#define RDB(arr, BO, QNOFS)                                                    \
  do { _Pragma("unroll") for (int n2 = 0; n2 < 2; ++n2) {                      \
    arr[n2][0] = RD16(pB0, (BO) + (QNOFS) + n2 * 2048);                        \
    arr[n2][1] = RD16(pB1, (BO) + (QNOFS) + n2 * 2048);                        \
  } SCHED0; } while (0)

// one C-quadrant (QM,QN): 16 MFMA, all-static acc indexing
#define MFQ(Af, Bf, QM, QN)                                                    \
  do {                                                                         \
    __builtin_amdgcn_s_setprio(1);                                             \
    _Pragma("unroll") for (int m2 = 0; m2 < 4; ++m2) {                         \
      _Pragma("unroll") for (int n2 = 0; n2 < 2; ++n2) {                       \
        acc[(QM)*4 + m2][(QN)*2 + n2] = __builtin_amdgcn_mfma_i32_16x16x64_i8( \
            Af[m2][0], Bf[n2][0], acc[(QM)*4 + m2][(QN)*2 + n2], 0, 0, 0);     \
        acc[(QM)*4 + m2][(QN)*2 + n2] = __builtin_amdgcn_mfma_i32_16x16x64_i8( \
            Af[m2][1], Bf[n2][1], acc[(QM)*4 + m2][(QN)*2 + n2], 0, 0, 0);     \
      }                                                                        \
    }                                                                          \
    __builtin_amdgcn_s_setprio(0);                                             \
  } while (0)

__global__ __launch_bounds__(512, 2) void gemm_i8_p(const signed char* __restrict__ A,
                                                    const signed char* __restrict__ Bw,
                                                    __hip_bfloat16* __restrict__ outh,
                                                    int* __restrict__ iacc0,
                                                    int* __restrict__ iacc1,
                                                    const float* __restrict__ scale,
                                                    int N, long K, int nt, int mode,
                                                    int nM, int nN) {
  __shared__ __align__(16) signed char lds[131072];  // A: [0,64K), B: [64K,128K)
  const int tid = threadIdx.x;
  const int lane = tid & 63;
  const int wave = tid >> 6;
  const int wm = wave >> 2, wn = wave & 3;  // 2x4 wave grid, 128x64 C per wave
  const int r15 = lane & 15, quad = lane >> 4, sw = lane & 7;

  // mt fastest (no XCD swizzle: same-mt => same XCD => A-panel L2 reuse)
  const int g = (int)blockIdx.x;
  const int mt = g % nM;
  const int rest = g / nM;
  const int ntl = rest % nN;
  const int z = rest / nN;
  const long m0 = (long)mt * 256, n0 = (long)ntl * 256;
  const signed char* Ab = A + m0 * K;
  const signed char* Bb = Bw + n0 * K;
  const long k0base = (long)z * nt * 128;

  // glds per-lane 32-bit global offsets (4 chunks; identical for A and B)
  unsigned voff[4];
#pragma unroll
  for (int i = 0; i < 4; ++i) {
    int c = wave * 64 + i * 512 + lane;
    int row = c >> 3;
    int blk = (c & 7) ^ (row & 7);  // pre-swizzled source column block
    voff[i] = (unsigned)row * (unsigned)K + (unsigned)(blk << 4);
  }

  // ds_read base pointers (k-slice 0/1 have different XOR'd column offsets)
  const signed char* pA0 = lds + (wm * 128 + r15) * 128 + ((quad ^ sw) << 4);
  const signed char* pA1 = lds + (wm * 128 + r15) * 128 + (((quad + 4) ^ sw) << 4);
  const signed char* pB0 = lds + 65536 + (wn * 64 + r15) * 128 + ((quad ^ sw) << 4);
  const signed char* pB1 = lds + 65536 + (wn * 64 + r15) * 128 + (((quad + 4) ^ sw) << 4);

  v4i a0[4][2], a1[4][2], b0[2][2], b1[2][2];
  v4i acc[8][4] = {};

  // stage pair i: one A-chunk + one B-chunk (2 glds, 2 KiB total per wave)
#define STAGE_PAIR(BO, KOFF, i)                                                \
  do {                                                                         \
    int cb = wave * 64 + (i) * 512;                                            \
    glds16(Ab + (KOFF) + voff[i], (void*)(lds + (BO) + cb * 16));              \
    glds16(Bb + (KOFF) + voff[i], (void*)(lds + 65536 + (BO) + cb * 16));      \
  } while (0)

  // ---- prologue: tile0 fully (8), tile1 partial (6); wait tile0; SBAR ----
  STAGE_PAIR(0, k0base, 0);
  STAGE_PAIR(0, k0base, 1);
  STAGE_PAIR(0, k0base, 2);
  STAGE_PAIR(0, k0base, 3);
  if (nt > 1) {
    STAGE_PAIR(32768, k0base + 128, 0);
    STAGE_PAIR(32768, k0base + 128, 1);
    STAGE_PAIR(32768, k0base + 128, 2);
    VMC(6);  // drains tile0's 8 (leaves tile1's 6)
  } else {
    VMC(0);
  }
  SBAR;

  for (int t = 0; t < nt; ++t) {
    const int bo = (t & 1) << 15;
    const int bn = bo ^ 32768;
    // ---- ph0: tail-stage t+1; reads a0,b0; SBAR; lgkm(0); MFQ00; SBAR ----
    if (t + 1 < nt) { STAGE_PAIR(bn, k0base + (long)(t + 1) * 128, 3); }
    RDA(a0, bo, 0);
    RDB(b0, bo, 0);
    SBAR;
    LGKM(0);
    MFQ(a0, b0, 0, 0);
    SBAR;
    // ---- ph1: reads b1; SBAR; lgkm(0); MFQ01; SBAR ----
    RDB(b1, bo, 4096);
    SBAR;
    LGKM(0);
    MFQ(a0, b1, 0, 1);
    SBAR;
    // ---- ph2: reads a1; SBAR; lgkm(0); MFQ10; SBAR ----
    RDA(a1, bo, 8192);
    SBAR;
    LGKM(0);
    MFQ(a1, b0, 1, 0);
    SBAR;  // after this: all waves' buf-p reads retired -> p overwrite-safe
    // ---- ph3 (read-free): stage 6 for t+2 into p; MFQ11; counted wait ----
    if (t + 2 < nt) {
      long kN2 = k0base + (long)(t + 2) * 128;
      STAGE_PAIR(bo, kN2, 0);
      STAGE_PAIR(bo, kN2, 1);
      STAGE_PAIR(bo, kN2, 2);
    }
    SBAR;
    MFQ(a1, b1, 1, 1);
    // VMC(6) only valid when ph3 just issued 6 new glds (queue = t+1's 8 +
    // t+2's 6). At t==nt-2 nothing was staged -> drain fully (r4 race fix).
    if (t + 2 < nt) { VMC(6); }
    else           { VMC(0); }
    SBAR;
  }

  // ---- epilogue: C layout col=lane&15, row=quad*4+reg (harness-verified) ----
  if (mode == 2) {
    int* iacc = z ? iacc1 : iacc0;
#pragma unroll
    for (int mi = 0; mi < 8; ++mi) {
#pragma unroll
      for (int r = 0; r < 4; ++r) {
        long m = m0 + wm * 128 + mi * 16 + quad * 4 + r;
        int* arow = iacc + m * N;
#pragma unroll
        for (int ni = 0; ni < 4; ++ni)
          arow[n0 + wn * 64 + ni * 16 + r15] = acc[mi][ni][r];
      }
    }
  } else {
#pragma unroll
    for (int mi = 0; mi < 8; ++mi) {
#pragma unroll
      for (int r = 0; r < 4; ++r) {
        long m = m0 + wm * 128 + mi * 16 + quad * 4 + r;
        float sm = scale[m];
        __hip_bfloat16* orow = outh + m * N;
#pragma unroll
        for (int ni = 0; ni < 4; ++ni) {
          float v = sm * (float)acc[mi][ni][r];
          orow[n0 + wn * 64 + ni * 16 + r15] = __float2bfloat16(gelu_f(v));
        }
      }
    }
  }
}

extern "C" void kernel_launch(void* const* d_in, const int* in_sizes, int n_in,
                              void* d_out, int out_size, void* d_ws, size_t ws_size,
                              hipStream_t stream) {
  const float* x    = (const float*)d_in[0];
  const float* ln1w = (const float*)d_in[1];
  const float* ln1b = (const float*)d_in[2];
  const float* ln2w = (const float*)d_in[3];
  const float* ln2b = (const float*)d_in[4];
  const float* Wg   = (const float*)d_in[5];
  const float* W1   = (const float*)d_in[6];
  const float* W2   = (const float*)d_in[7];
  const int* is0    = (const int*)d_in[8];
  const int* is1    = (const int*)d_in[9];
  const int* iv     = (const int*)d_in[10];
  float* out = (float*)d_out;

  // workspace layout, peak ~234 MB (unchanged from verified layout):
  char* ws = (char*)d_ws;
  float* sums = (float*)ws;                                   // 3 floats (+pad)
  signed char* t_g = (signed char*)(ws + 256);                // 15,728,640
  signed char* t_1 = t_g + 15728640;                          //  4,194,304
  signed char* t_2 = t_1 + 4194304;                           //  4,194,304
  float* rowmax1 = (float*)(t_2 + 4194304);                   // 32 KB
  float* s1  = rowmax1 + 8192;
  float* s2  = s1 + 8192;
  float* s3  = s2 + 8192;
  float* xag = s3 + 8192;
  int* acc1b = (int*)xag;
  signed char* hq = (signed char*)(xag + 8388608);            //  8.39 MB
  float* xn = (float*)(hq + 8388608);
  int* acc1a = (int*)xn;
  signed char* q3 = (signed char*)xn;
  signed char* Aq = (signed char*)(xn + 8388608);
  unsigned short* gg = (unsigned short*)Aq;
  int* acc3a = (int*)Aq;
  int* acc3b = acc3a + 8192l * 1024;

  hipMemsetAsync(sums, 0, 64, stream);
  // prep1: absum3 (1024 blocks) + LN1/rowmax (8192 blocks)
  prep1_kernel<<<9216, 256, 0, stream>>>(Wg, W1, W2, sums, x, ln1w, ln1b, xn, rowmax1);
  // prep2: ternarize3 (2048 blocks) + quantA vec16 (8192 blocks)
  prep2_kernel<<<10240, 256, 0, stream>>>(Wg, W1, W2, t_g, t_1, t_2, sums,
                                          xn, is0, is1, iv, rowmax1, Aq, s1);
  // GEMM1: M=8192 N=1024 K=15360, split-K=2 -> 32*4*2 = 256 blocks (1/CU)
  gemm_i8_p<<<256, 512, 0, stream>>>(Aq, t_g, nullptr, acc1a, acc1b, nullptr,
                                     1024, 15360L, 60, 2, 32, 4);
  ln_quant_acc_kernel<<<8192, 256, 0, stream>>>(acc1a, acc1b, x, s1, ln2w, ln2b, xag, hq, s2,
                                                &sums[1], 1.f / 4194304.f);
  // GEMM2: M=8192 N=4096 K=1024, gelu -> bf16, 32*16 = 512 blocks
  gemm_i8_p<<<512, 512, 0, stream>>>(hq, t_1, (__hip_bfloat16*)gg, nullptr, nullptr,
                                     s2, 4096, 1024L, 8, 1, 32, 16);
  rowquant4k_kernel<<<8192, 256, 0, stream>>>(gg, q3, s3, &sums[2], 1.f / 4194304.f);
  // GEMM3: M=8192 N=1024 K=4096, split-K=2 -> 256 blocks
  gemm_i8_p<<<256, 512, 0, stream>>>(q3, t_2, nullptr, acc3a, acc3b, nullptr,
                                     1024, 4096L, 16, 2, 32, 4);
  reduce3_kernel<<<8192, 256, 0, stream>>>(acc3a, acc3b, xag, s3, out);
}